// Round 3
// baseline (2036.936 us; speedup 1.0000x reference)
//
#include <hip/hip_runtime.h>

constexpr int NN   = 20000;
constexpr int EE   = 200000;
constexpr int IN_D = 500;
constexpr int HID  = 256;
constexpr int OUT_D= 16;
constexpr int MH   = 64;

// ---------------------------------------------------------------------------
// Kernel A: h = t1 @ Win2.T + bin2 with t1 = relu(x @ Win1.T + bin1)
// Also As = h @ Wa.T, Bs = h @ Wb.T  (Wa = Wm1[:, :256], Wb = Wm1[:, 256:])
// 8 nodes per block, 256 threads.  ALL INPUTS F32.
// ---------------------------------------------------------------------------
__global__ __launch_bounds__(256) void k_in_mlp(
    const float* __restrict__ x,    const float* __restrict__ Win1, const float* __restrict__ bin1,
    const float* __restrict__ Win2, const float* __restrict__ bin2, const float* __restrict__ Wm1,
    float* __restrict__ h, float* __restrict__ As, float* __restrict__ Bs)
{
    __shared__ float xs[8 * IN_D];   // 16 KB, row ni at offset ni*500 (2000B-aligned)
    __shared__ float t1s[8][MH];     // 2 KB
    __shared__ float hs[8][HID];     // 8 KB
    const int tid = threadIdx.x;
    const int node0 = blockIdx.x * 8;

    // stage 8 contiguous x rows (4000 floats = 1000 float4)
    const float4* xsrc = (const float4*)(x + (size_t)node0 * IN_D);
    float4* xdst = (float4*)xs;
    for (int i = tid; i < 8 * IN_D / 4; i += 256) xdst[i] = xsrc[i];
    __syncthreads();

    // phase 1: t1[8][64] = relu(x @ Win1.T + bin1)
    #pragma unroll
    for (int r = 0; r < 2; ++r) {
        int o = tid + r * 256;
        int ni = o >> 6, c = o & 63;
        float acc = bin1[c];
        const float4* wr = (const float4*)(Win1 + (size_t)c * IN_D);
        const float4* xr = (const float4*)(xs + ni * IN_D);
        #pragma unroll 5
        for (int k = 0; k < IN_D / 4; ++k) {
            float4 wv = wr[k], xv = xr[k];
            acc += xv.x * wv.x + xv.y * wv.y + xv.z * wv.z + xv.w * wv.w;
        }
        t1s[ni][c] = fmaxf(acc, 0.f);
    }
    __syncthreads();

    // phase 2: h[8][256] = t1 @ Win2.T + bin2   (no relu)
    #pragma unroll
    for (int r = 0; r < 8; ++r) {
        int o = tid + r * 256;
        int ni = o >> 8, c = o & 255;
        float acc = bin2[c];
        const float4* wr = (const float4*)(Win2 + (size_t)c * MH);
        const float4* tr = (const float4*)(t1s[ni]);
        #pragma unroll
        for (int k = 0; k < MH / 4; ++k) {
            float4 wv = wr[k], tv = tr[k];
            acc += tv.x * wv.x + tv.y * wv.y + tv.z * wv.z + tv.w * wv.w;
        }
        hs[ni][c] = acc;
        h[(size_t)(node0 + ni) * HID + c] = acc;
    }
    __syncthreads();

    // phase 3: As/Bs[8][64] = h @ Wa.T / h @ Wb.T   (no bias here)
    #pragma unroll
    for (int r = 0; r < 4; ++r) {
        int o = tid + r * 256;
        int which = o >> 9, rem = o & 511;
        int ni = rem >> 6, c = rem & 63;
        const float4* wr = (const float4*)(Wm1 + (size_t)c * (2 * HID) + which * HID);
        const float4* hr = (const float4*)(hs[ni]);
        float acc = 0.f;
        #pragma unroll 8
        for (int k = 0; k < HID / 4; ++k) {
            float4 wv = wr[k], hv = hr[k];
            acc += hv.x * wv.x + hv.y * wv.y + hv.z * wv.z + hv.w * wv.w;
        }
        float* dstp = which ? Bs : As;
        dstp[(size_t)(node0 + ni) * MH + c] = acc;
    }
}

// ---------------------------------------------------------------------------
// Kernel B: per-edge messages Fs, Ft (E x 16 each).
// One wave per edge; 4 edges per block.
// ---------------------------------------------------------------------------
__global__ __launch_bounds__(256) void k_edge_msg(
    const int* __restrict__ ei, const float* __restrict__ As, const float* __restrict__ Bs,
    const float* __restrict__ bm1, const float* __restrict__ Wm2, const float* __restrict__ bm2,
    float* __restrict__ Fs, float* __restrict__ Ft)
{
    __shared__ float plds[4][2][64];  // 2 KB
    const int tid = threadIdx.x;
    const int w = tid >> 6, t = tid & 63;
    const int e = blockIdx.x * 4 + w;
    const int src = ei[e], dst = ei[EE + e];
    float a_s = As[(size_t)src * MH + t], b_d = Bs[(size_t)dst * MH + t];
    float a_d = As[(size_t)dst * MH + t], b_s = Bs[(size_t)src * MH + t];
    float bm = bm1[t];
    plds[w][0][t] = fmaxf(a_s + b_d + bm, 0.f);  // pre-m1
    plds[w][1][t] = fmaxf(a_d + b_s + bm, 0.f);  // pre-m2
    __syncthreads();
    if (tid < 128) {
        int el = tid >> 5, rem = tid & 31, which = rem >> 4, j = rem & 15;
        float acc = bm2[j];
        const float4* wr = (const float4*)(Wm2 + (size_t)j * MH);
        const float4* p = (const float4*)(plds[el][which]);
        #pragma unroll
        for (int k = 0; k < MH / 4; ++k) {
            float4 wv = wr[k], pv = p[k];
            acc += pv.x * wv.x + pv.y * wv.y + pv.z * wv.z + pv.w * wv.w;
        }
        int eg = blockIdx.x * 4 + el;
        (which ? Ft : Fs)[(size_t)eg * 16 + j] = acc;
    }
}

// ---------------------------------------------------------------------------
// Kernel C: per node, optionally xb -= relu(LH) (written back), then
// H[n] = (Wd1.T @ xb[n]) @ Wd2.T.  16 nodes/block (4 per wave).
// Wd2 staged into LDS, padded stride 68 (conflict-free).
// ---------------------------------------------------------------------------
__global__ __launch_bounds__(256) void k_node_H(
    float* __restrict__ xb, const float* __restrict__ LH,
    const float* __restrict__ Wd1l, const float* __restrict__ Wd2l,
    float* __restrict__ H)
{
    __shared__ float wt[64][68];     // 17.4 KB, wt[g][f] = Wd2[g][f]
    __shared__ float tl[4][4][64];   // per-wave tmp, 4 KB
    const int tid = threadIdx.x;
    const int w = tid >> 6, t = tid & 63;

    for (int i = tid; i < 4096; i += 256) {
        int g = i >> 6, f = i & 63;
        wt[g][f] = Wd2l[i];
    }
    float wd1[16];
    #pragma unroll
    for (int i = 0; i < 16; ++i) wd1[i] = Wd1l[i];
    __syncthreads();

    for (int rep = 0; rep < 4; ++rep) {
        const int n = blockIdx.x * 16 + w * 4 + rep;
        float xv[4];
        #pragma unroll
        for (int j = 0; j < 4; ++j) {
            size_t idx = (size_t)n * HID + j * 64 + t;
            float v = xb[idx];
            if (LH) { v -= fmaxf(LH[idx], 0.f); xb[idx] = v; }
            xv[j] = v;
        }
        // tmp[i][f=t] = sum_j Wd1[j][i] * xv[j]
        #pragma unroll
        for (int i = 0; i < 4; ++i)
            tl[w][i][t] = wd1[0 + i] * xv[0] + wd1[4 + i] * xv[1] +
                          wd1[8 + i] * xv[2] + wd1[12 + i] * xv[3];
        __syncthreads();
        float acc0 = 0, acc1 = 0, acc2 = 0, acc3 = 0;
        #pragma unroll
        for (int f = 0; f < 64; f += 4) {
            float4 wv = *(const float4*)&wt[t][f];
            float4 t0 = *(const float4*)&tl[w][0][f];
            float4 t1 = *(const float4*)&tl[w][1][f];
            float4 t2 = *(const float4*)&tl[w][2][f];
            float4 t3 = *(const float4*)&tl[w][3][f];
            acc0 += t0.x * wv.x + t0.y * wv.y + t0.z * wv.z + t0.w * wv.w;
            acc1 += t1.x * wv.x + t1.y * wv.y + t1.z * wv.z + t1.w * wv.w;
            acc2 += t2.x * wv.x + t2.y * wv.y + t2.z * wv.z + t2.w * wv.w;
            acc3 += t3.x * wv.x + t3.y * wv.y + t3.z * wv.z + t3.w * wv.w;
        }
        __syncthreads();
        size_t base = (size_t)n * HID + t;
        H[base + 0 * 64] = acc0;
        H[base + 1 * 64] = acc1;
        H[base + 2 * 64] = acc2;
        H[base + 3 * 64] = acc3;
    }
}

// ---------------------------------------------------------------------------
// Kernel D: per edge: Bx = Ft@H[dst] - Fs@H[src];
//   LH[src] -= Fs.T@Bx  (atomic),  LH[dst] += Ft.T@Bx  (atomic).
// One wave per edge, lane = column.
// ---------------------------------------------------------------------------
__global__ __launch_bounds__(256) void k_edge_diff(
    const int* __restrict__ ei, const float* __restrict__ Fs, const float* __restrict__ Ft,
    const float* __restrict__ H, float* __restrict__ LH)
{
    const int tid = threadIdx.x;
    const int w = tid >> 6, t = tid & 63;
    const int e = blockIdx.x * 4 + w;
    const int src = ei[e], dst = ei[EE + e];

    const float4* fsp = (const float4*)(Fs + (size_t)e * 16);
    const float4* ftp = (const float4*)(Ft + (size_t)e * 16);
    float4 fs0 = fsp[0], fs1 = fsp[1], fs2 = fsp[2], fs3 = fsp[3];
    float4 ft0 = ftp[0], ft1 = ftp[1], ft2 = ftp[2], ft3 = ftp[3];

    float hs0 = H[(size_t)src * HID + 0 * 64 + t];
    float hs1 = H[(size_t)src * HID + 1 * 64 + t];
    float hs2 = H[(size_t)src * HID + 2 * 64 + t];
    float hs3 = H[(size_t)src * HID + 3 * 64 + t];
    float hd0 = H[(size_t)dst * HID + 0 * 64 + t];
    float hd1 = H[(size_t)dst * HID + 1 * 64 + t];
    float hd2 = H[(size_t)dst * HID + 2 * 64 + t];
    float hd3 = H[(size_t)dst * HID + 3 * 64 + t];

    float bx0 = ft0.x * hd0 + ft0.y * hd1 + ft0.z * hd2 + ft0.w * hd3
              - (fs0.x * hs0 + fs0.y * hs1 + fs0.z * hs2 + fs0.w * hs3);
    float bx1 = ft1.x * hd0 + ft1.y * hd1 + ft1.z * hd2 + ft1.w * hd3
              - (fs1.x * hs0 + fs1.y * hs1 + fs1.z * hs2 + fs1.w * hs3);
    float bx2 = ft2.x * hd0 + ft2.y * hd1 + ft2.z * hd2 + ft2.w * hd3
              - (fs2.x * hs0 + fs2.y * hs1 + fs2.z * hs2 + fs2.w * hs3);
    float bx3 = ft3.x * hd0 + ft3.y * hd1 + ft3.z * hd2 + ft3.w * hd3
              - (fs3.x * hs0 + fs3.y * hs1 + fs3.z * hs2 + fs3.w * hs3);

    float u0 = fs0.x * bx0 + fs1.x * bx1 + fs2.x * bx2 + fs3.x * bx3;
    float u1 = fs0.y * bx0 + fs1.y * bx1 + fs2.y * bx2 + fs3.y * bx3;
    float u2 = fs0.z * bx0 + fs1.z * bx1 + fs2.z * bx2 + fs3.z * bx3;
    float u3 = fs0.w * bx0 + fs1.w * bx1 + fs2.w * bx2 + fs3.w * bx3;
    float v0 = ft0.x * bx0 + ft1.x * bx1 + ft2.x * bx2 + ft3.x * bx3;
    float v1 = ft0.y * bx0 + ft1.y * bx1 + ft2.y * bx2 + ft3.y * bx3;
    float v2 = ft0.z * bx0 + ft1.z * bx1 + ft2.z * bx2 + ft3.z * bx3;
    float v3 = ft0.w * bx0 + ft1.w * bx1 + ft2.w * bx2 + ft3.w * bx3;

    float* ls = LH + (size_t)src * HID + t;
    float* ld = LH + (size_t)dst * HID + t;
    atomicAdd(ls + 0 * 64, -u0);
    atomicAdd(ls + 1 * 64, -u1);
    atomicAdd(ls + 2 * 64, -u2);
    atomicAdd(ls + 3 * 64, -u3);
    atomicAdd(ld + 0 * 64, v0);
    atomicAdd(ld + 1 * 64, v1);
    atomicAdd(ld + 2 * 64, v2);
    atomicAdd(ld + 3 * 64, v3);
}

// ---------------------------------------------------------------------------
// Kernel F: out = relu((xb - relu(LH)) @ Wo1.T + bo1) @ Wo2.T + bo2, F32 out.
// 8 nodes per block.
// ---------------------------------------------------------------------------
__global__ __launch_bounds__(256) void k_out_mlp(
    const float* __restrict__ xb, const float* __restrict__ LH,
    const float* __restrict__ Wo1, const float* __restrict__ bo1,
    const float* __restrict__ Wo2, const float* __restrict__ bo2,
    float* __restrict__ out)
{
    __shared__ float xr[8][HID];  // 8 KB
    __shared__ float t1s[8][MH];  // 2 KB
    const int tid = threadIdx.x;
    const int node0 = blockIdx.x * 8;

    #pragma unroll
    for (int r = 0; r < 8; ++r) {
        int o = tid + r * 256;
        int ni = o >> 8, c = o & 255;
        size_t idx = (size_t)(node0 + ni) * HID + c;
        xr[ni][c] = xb[idx] - fmaxf(LH[idx], 0.f);
    }
    __syncthreads();

    #pragma unroll
    for (int r = 0; r < 2; ++r) {
        int o = tid + r * 256;
        int ni = o >> 6, c = o & 63;
        float acc = bo1[c];
        const float4* wr = (const float4*)(Wo1 + (size_t)c * HID);
        const float4* hr = (const float4*)(xr[ni]);
        #pragma unroll 8
        for (int k = 0; k < HID / 4; ++k) {
            float4 wv = wr[k], hv = hr[k];
            acc += hv.x * wv.x + hv.y * wv.y + hv.z * wv.z + hv.w * wv.w;
        }
        t1s[ni][c] = fmaxf(acc, 0.f);
    }
    __syncthreads();

    if (tid < 128) {
        int ni = tid >> 4, j = tid & 15;
        float acc = bo2[j];
        const float4* wr = (const float4*)(Wo2 + (size_t)j * MH);
        const float4* tr = (const float4*)(t1s[ni]);
        #pragma unroll
        for (int k = 0; k < MH / 4; ++k) {
            float4 wv = wr[k], tv = tr[k];
            acc += tv.x * wv.x + tv.y * wv.y + tv.z * wv.z + tv.w * wv.w;
        }
        out[(size_t)(node0 + ni) * OUT_D + j] = acc;
    }
}

// ---------------------------------------------------------------------------
// Workspace (floats): h | Fs | Ft | H(=As/Bs alias) | LH  = 21.76M = 87 MB
// ---------------------------------------------------------------------------
extern "C" void kernel_launch(void* const* d_in, const int* in_sizes, int n_in,
                              void* d_out, int out_size, void* d_ws, size_t ws_size,
                              hipStream_t stream)
{
    const float* x    = (const float*)d_in[0];
    const int*   ei   = (const int*)d_in[1];
    const float* Win1 = (const float*)d_in[2];
    const float* bin1 = (const float*)d_in[3];
    const float* Win2 = (const float*)d_in[4];
    const float* bin2 = (const float*)d_in[5];
    const float* Wm1  = (const float*)d_in[6];
    const float* bm1  = (const float*)d_in[7];
    const float* Wm2  = (const float*)d_in[8];
    const float* bm2  = (const float*)d_in[9];
    const float* Wd1  = (const float*)d_in[10];
    const float* Wd2  = (const float*)d_in[11];
    const float* Wo1  = (const float*)d_in[12];
    const float* bo1  = (const float*)d_in[13];
    const float* Wo2  = (const float*)d_in[14];
    const float* bo2  = (const float*)d_in[15];
    float* out = (float*)d_out;

    float* ws = (float*)d_ws;
    float* h  = ws;                          // N*256
    float* Fs = h  + (size_t)NN * HID;       // E*16
    float* Ft = Fs + (size_t)EE * 16;        // E*16
    float* H  = Ft + (size_t)EE * 16;        // N*256
    float* LH = H  + (size_t)NN * HID;       // N*256
    float* As = H;                           // aliases H (dead before H written)
    float* Bs = H  + (size_t)NN * MH;

    k_in_mlp<<<NN / 8, 256, 0, stream>>>(x, Win1, bin1, Win2, bin2, Wm1, h, As, Bs);
    k_edge_msg<<<EE / 4, 256, 0, stream>>>(ei, As, Bs, bm1, Wm2, bm2, Fs, Ft);

    // layer 0
    hipMemsetAsync(LH, 0, (size_t)NN * HID * sizeof(float), stream);
    k_node_H<<<NN / 16, 256, 0, stream>>>(h, nullptr, Wd1, Wd2, H);
    k_edge_diff<<<EE / 4, 256, 0, stream>>>(ei, Fs, Ft, H, LH);

    // layer 1 (k_node_H consumes LH of layer 0, updates xb in place)
    k_node_H<<<NN / 16, 256, 0, stream>>>(h, LH, Wd1 + 16, Wd2 + 4096, H);
    hipMemsetAsync(LH, 0, (size_t)NN * HID * sizeof(float), stream);
    k_edge_diff<<<EE / 4, 256, 0, stream>>>(ei, Fs, Ft, H, LH);

    k_out_mlp<<<NN / 8, 256, 0, stream>>>(h, LH, Wo1, bo1, Wo2, bo2, out);
}

// Round 4
// 1241.766 us; speedup vs baseline: 1.6404x; 1.6404x over previous
//
#include <hip/hip_runtime.h>

constexpr int NN   = 20000;
constexpr int EE   = 200000;
constexpr int IN_D = 500;
constexpr int HID  = 256;
constexpr int OUT_D= 16;
constexpr int MH   = 64;

// ===========================================================================
// k_in_mlp — lane = node, weights wave-uniform (s_load), 64 nodes/block.
//   phase 1: t1 = relu(x @ Win1.T + bin1)      (c split 16/wave)
//   phase 2: h  = t1 @ Win2.T + bin2           (c split 64/wave, h -> global)
//   phase 3: As = h @ Wa.T, Bs = h @ Wb.T      (vc split 32/wave, h from L1/L2)
// LDS: xs[64][101] (25.9 KB) + t1s[64][65] (16.6 KB) = 42.5 KB -> 3 blocks/CU
// ===========================================================================
__global__ __launch_bounds__(256, 4) void k_in_mlp(
    const float* __restrict__ x,    const float* __restrict__ Win1, const float* __restrict__ bin1,
    const float* __restrict__ Win2, const float* __restrict__ bin2, const float* __restrict__ Wm1,
    float* __restrict__ h, float* __restrict__ As, float* __restrict__ Bs)
{
    __shared__ float xs[64 * 101];   // chunk of x rows, pad 101 (odd -> conflict-free)
    __shared__ float t1s[64 * 65];   // t1 rows, pad 65
    const int tid  = threadIdx.x;
    const int w    = __builtin_amdgcn_readfirstlane(tid >> 6);  // wave id 0..3
    const int lane = tid & 63;                                   // = local node
    const int node0 = blockIdx.x * 64;
    const int g = min(node0 + lane, NN - 1);
    const bool valid = (node0 + lane) < NN;

    // ---------------- phase 1 ----------------
    float acc1[16];
    #pragma unroll
    for (int i = 0; i < 16; ++i) acc1[i] = 0.f;

    for (int j = 0; j < 5; ++j) {            // K-chunks of 100
        __syncthreads();
        // stage x[:, 100j .. 100j+100) coalesced: 1600 float4
        for (int i = tid; i < 1600; i += 256) {
            int n = i / 25, k4 = i % 25;
            int gr = min(node0 + n, NN - 1);
            float4 v = ((const float4*)x)[(size_t)gr * 125 + j * 25 + k4];
            float* d = &xs[n * 101 + k4 * 4];
            d[0] = v.x; d[1] = v.y; d[2] = v.z; d[3] = v.w;
        }
        __syncthreads();
        for (int kt = 0; kt < 25; ++kt) {    // k-tiles of 4
            float xv0 = xs[lane * 101 + kt * 4 + 0];
            float xv1 = xs[lane * 101 + kt * 4 + 1];
            float xv2 = xs[lane * 101 + kt * 4 + 2];
            float xv3 = xs[lane * 101 + kt * 4 + 3];
            #pragma unroll
            for (int cc = 0; cc < 16; ++cc) {
                const int c = w * 16 + cc;                       // wave-uniform
                const float* wr = Win1 + (size_t)c * IN_D + j * 100 + kt * 4;
                acc1[cc] += xv0 * wr[0] + xv1 * wr[1] + xv2 * wr[2] + xv3 * wr[3];
            }
        }
    }
    __syncthreads();
    #pragma unroll
    for (int cc = 0; cc < 16; ++cc) {
        const int c = w * 16 + cc;
        t1s[lane * 65 + c] = fmaxf(acc1[cc] + bin1[c], 0.f);
    }
    __syncthreads();

    // ---------------- phase 2 ----------------
    float acc2[64];
    #pragma unroll
    for (int i = 0; i < 64; ++i) acc2[i] = 0.f;
    for (int kt = 0; kt < 8; ++kt) {         // k-tiles of 8 over MH=64
        float tv[8];
        #pragma unroll
        for (int i = 0; i < 8; ++i) tv[i] = t1s[lane * 65 + kt * 8 + i];
        #pragma unroll
        for (int cc = 0; cc < 64; ++cc) {
            const int c = w * 64 + cc;
            const float* wr = Win2 + (size_t)c * MH + kt * 8;
            acc2[cc] += tv[0]*wr[0] + tv[1]*wr[1] + tv[2]*wr[2] + tv[3]*wr[3]
                      + tv[4]*wr[4] + tv[5]*wr[5] + tv[6]*wr[6] + tv[7]*wr[7];
        }
    }
    if (valid) {
        float* hp = h + (size_t)g * HID + w * 64;
        #pragma unroll
        for (int c4 = 0; c4 < 16; ++c4) {
            float4 v;
            v.x = acc2[c4*4+0] + bin2[w*64 + c4*4+0];
            v.y = acc2[c4*4+1] + bin2[w*64 + c4*4+1];
            v.z = acc2[c4*4+2] + bin2[w*64 + c4*4+2];
            v.w = acc2[c4*4+3] + bin2[w*64 + c4*4+3];
            *(float4*)(hp + c4 * 4) = v;
        }
    }
    __threadfence_block();
    __syncthreads();   // h of this block's 64 nodes now visible (per-CU L1)

    // ---------------- phase 3 ----------------
    float acc3[32];
    #pragma unroll
    for (int i = 0; i < 32; ++i) acc3[i] = 0.f;
    const float* hrow = h + (size_t)g * HID;
    for (int kt = 0; kt < 32; ++kt) {        // k-tiles of 8 over HID=256
        float4 a = *(const float4*)(hrow + kt * 8);
        float4 b = *(const float4*)(hrow + kt * 8 + 4);
        #pragma unroll
        for (int jj = 0; jj < 32; ++jj) {
            const int vc = w * 32 + jj;      // 0..127: A cols then B cols
            const int which = vc >> 6;
            const int c = vc & 63;
            const float* wr = Wm1 + (size_t)c * (2 * HID) + which * HID + kt * 8;
            acc3[jj] += a.x*wr[0] + a.y*wr[1] + a.z*wr[2] + a.w*wr[3]
                      + b.x*wr[4] + b.y*wr[5] + b.z*wr[6] + b.w*wr[7];
        }
    }
    if (valid) {
        float* dst = (w < 2) ? (As + (size_t)g * MH + w * 32)
                             : (Bs + (size_t)g * MH + (w - 2) * 32);
        #pragma unroll
        for (int j4 = 0; j4 < 8; ++j4) {
            float4 v;
            v.x = acc3[j4*4+0]; v.y = acc3[j4*4+1];
            v.z = acc3[j4*4+2]; v.w = acc3[j4*4+3];
            *(float4*)(dst + j4 * 4) = v;
        }
    }
}

// ---------------------------------------------------------------------------
// Kernel B: per-edge messages Fs, Ft (E x 16 each). One wave per edge.
// ---------------------------------------------------------------------------
__global__ __launch_bounds__(256) void k_edge_msg(
    const int* __restrict__ ei, const float* __restrict__ As, const float* __restrict__ Bs,
    const float* __restrict__ bm1, const float* __restrict__ Wm2, const float* __restrict__ bm2,
    float* __restrict__ Fs, float* __restrict__ Ft)
{
    __shared__ float plds[4][2][64];
    const int tid = threadIdx.x;
    const int w = tid >> 6, t = tid & 63;
    const int e = blockIdx.x * 4 + w;
    const int src = ei[e], dst = ei[EE + e];
    float a_s = As[(size_t)src * MH + t], b_d = Bs[(size_t)dst * MH + t];
    float a_d = As[(size_t)dst * MH + t], b_s = Bs[(size_t)src * MH + t];
    float bm = bm1[t];
    plds[w][0][t] = fmaxf(a_s + b_d + bm, 0.f);
    plds[w][1][t] = fmaxf(a_d + b_s + bm, 0.f);
    __syncthreads();
    if (tid < 128) {
        int el = tid >> 5, rem = tid & 31, which = rem >> 4, j = rem & 15;
        float acc = bm2[j];
        const float4* wr = (const float4*)(Wm2 + (size_t)j * MH);
        const float4* p = (const float4*)(plds[el][which]);
        #pragma unroll
        for (int k = 0; k < MH / 4; ++k) {
            float4 wv = wr[k], pv = p[k];
            acc += pv.x * wv.x + pv.y * wv.y + pv.z * wv.z + pv.w * wv.w;
        }
        int eg = blockIdx.x * 4 + el;
        (which ? Ft : Fs)[(size_t)eg * 16 + j] = acc;
    }
}

// ---------------------------------------------------------------------------
// Kernel C: per node, optionally xb -= relu(LH), then H = (Wd1.T@xb)@Wd2.T
// ---------------------------------------------------------------------------
__global__ __launch_bounds__(256) void k_node_H(
    float* __restrict__ xb, const float* __restrict__ LH,
    const float* __restrict__ Wd1l, const float* __restrict__ Wd2l,
    float* __restrict__ H)
{
    __shared__ float wt[64][68];
    __shared__ float tl[4][4][64];
    const int tid = threadIdx.x;
    const int w = tid >> 6, t = tid & 63;

    for (int i = tid; i < 4096; i += 256) {
        int gg = i >> 6, f = i & 63;
        wt[gg][f] = Wd2l[i];
    }
    float wd1[16];
    #pragma unroll
    for (int i = 0; i < 16; ++i) wd1[i] = Wd1l[i];
    __syncthreads();

    for (int rep = 0; rep < 4; ++rep) {
        const int n = blockIdx.x * 16 + w * 4 + rep;
        float xv[4];
        #pragma unroll
        for (int j = 0; j < 4; ++j) {
            size_t idx = (size_t)n * HID + j * 64 + t;
            float v = xb[idx];
            if (LH) { v -= fmaxf(LH[idx], 0.f); xb[idx] = v; }
            xv[j] = v;
        }
        #pragma unroll
        for (int i = 0; i < 4; ++i)
            tl[w][i][t] = wd1[0 + i] * xv[0] + wd1[4 + i] * xv[1] +
                          wd1[8 + i] * xv[2] + wd1[12 + i] * xv[3];
        __syncthreads();
        float acc0 = 0, acc1 = 0, acc2 = 0, acc3 = 0;
        #pragma unroll
        for (int f = 0; f < 64; f += 4) {
            float4 wv = *(const float4*)&wt[t][f];
            float4 t0 = *(const float4*)&tl[w][0][f];
            float4 t1 = *(const float4*)&tl[w][1][f];
            float4 t2 = *(const float4*)&tl[w][2][f];
            float4 t3 = *(const float4*)&tl[w][3][f];
            acc0 += t0.x * wv.x + t0.y * wv.y + t0.z * wv.z + t0.w * wv.w;
            acc1 += t1.x * wv.x + t1.y * wv.y + t1.z * wv.z + t1.w * wv.w;
            acc2 += t2.x * wv.x + t2.y * wv.y + t2.z * wv.z + t2.w * wv.w;
            acc3 += t3.x * wv.x + t3.y * wv.y + t3.z * wv.z + t3.w * wv.w;
        }
        __syncthreads();
        size_t base = (size_t)n * HID + t;
        H[base + 0 * 64] = acc0;
        H[base + 1 * 64] = acc1;
        H[base + 2 * 64] = acc2;
        H[base + 3 * 64] = acc3;
    }
}

// ---------------------------------------------------------------------------
// Kernel D: per edge: Bx = Ft@H[dst] - Fs@H[src]; scatter ∓F.T@Bx into LH.
// ---------------------------------------------------------------------------
__global__ __launch_bounds__(256) void k_edge_diff(
    const int* __restrict__ ei, const float* __restrict__ Fs, const float* __restrict__ Ft,
    const float* __restrict__ H, float* __restrict__ LH)
{
    const int tid = threadIdx.x;
    const int w = tid >> 6, t = tid & 63;
    const int e = blockIdx.x * 4 + w;
    const int src = ei[e], dst = ei[EE + e];

    const float4* fsp = (const float4*)(Fs + (size_t)e * 16);
    const float4* ftp = (const float4*)(Ft + (size_t)e * 16);
    float4 fs0 = fsp[0], fs1 = fsp[1], fs2 = fsp[2], fs3 = fsp[3];
    float4 ft0 = ftp[0], ft1 = ftp[1], ft2 = ftp[2], ft3 = ftp[3];

    float hs0 = H[(size_t)src * HID + 0 * 64 + t];
    float hs1 = H[(size_t)src * HID + 1 * 64 + t];
    float hs2 = H[(size_t)src * HID + 2 * 64 + t];
    float hs3 = H[(size_t)src * HID + 3 * 64 + t];
    float hd0 = H[(size_t)dst * HID + 0 * 64 + t];
    float hd1 = H[(size_t)dst * HID + 1 * 64 + t];
    float hd2 = H[(size_t)dst * HID + 2 * 64 + t];
    float hd3 = H[(size_t)dst * HID + 3 * 64 + t];

    float bx0 = ft0.x * hd0 + ft0.y * hd1 + ft0.z * hd2 + ft0.w * hd3
              - (fs0.x * hs0 + fs0.y * hs1 + fs0.z * hs2 + fs0.w * hs3);
    float bx1 = ft1.x * hd0 + ft1.y * hd1 + ft1.z * hd2 + ft1.w * hd3
              - (fs1.x * hs0 + fs1.y * hs1 + fs1.z * hs2 + fs1.w * hs3);
    float bx2 = ft2.x * hd0 + ft2.y * hd1 + ft2.z * hd2 + ft2.w * hd3
              - (fs2.x * hs0 + fs2.y * hs1 + fs2.z * hs2 + fs2.w * hs3);
    float bx3 = ft3.x * hd0 + ft3.y * hd1 + ft3.z * hd2 + ft3.w * hd3
              - (fs3.x * hs0 + fs3.y * hs1 + fs3.z * hs2 + fs3.w * hs3);

    float u0 = fs0.x * bx0 + fs1.x * bx1 + fs2.x * bx2 + fs3.x * bx3;
    float u1 = fs0.y * bx0 + fs1.y * bx1 + fs2.y * bx2 + fs3.y * bx3;
    float u2 = fs0.z * bx0 + fs1.z * bx1 + fs2.z * bx2 + fs3.z * bx3;
    float u3 = fs0.w * bx0 + fs1.w * bx1 + fs2.w * bx2 + fs3.w * bx3;
    float v0 = ft0.x * bx0 + ft1.x * bx1 + ft2.x * bx2 + ft3.x * bx3;
    float v1 = ft0.y * bx0 + ft1.y * bx1 + ft2.y * bx2 + ft3.y * bx3;
    float v2 = ft0.z * bx0 + ft1.z * bx1 + ft2.z * bx2 + ft3.z * bx3;
    float v3 = ft0.w * bx0 + ft1.w * bx1 + ft2.w * bx2 + ft3.w * bx3;

    float* ls = LH + (size_t)src * HID + t;
    float* ld = LH + (size_t)dst * HID + t;
    atomicAdd(ls + 0 * 64, -u0);
    atomicAdd(ls + 1 * 64, -u1);
    atomicAdd(ls + 2 * 64, -u2);
    atomicAdd(ls + 3 * 64, -u3);
    atomicAdd(ld + 0 * 64, v0);
    atomicAdd(ld + 1 * 64, v1);
    atomicAdd(ld + 2 * 64, v2);
    atomicAdd(ld + 3 * 64, v3);
}

// ===========================================================================
// k_out_mlp — same lane=node / uniform-weight structure. 64 nodes/block.
//   phase A: t1 = relu((xb - relu(LH)) @ Wo1.T + bo1)   (c split 16/wave)
//   phase B: out = t1 @ Wo2.T + bo2                     (j split 4/wave)
// LDS: xr[64][129] (33 KB) + t1s[64][65] (16.6 KB) = 49.6 KB
// ===========================================================================
__global__ __launch_bounds__(256, 4) void k_out_mlp(
    const float* __restrict__ xb, const float* __restrict__ LH,
    const float* __restrict__ Wo1, const float* __restrict__ bo1,
    const float* __restrict__ Wo2, const float* __restrict__ bo2,
    float* __restrict__ out)
{
    __shared__ float xr[64 * 129];
    __shared__ float t1s[64 * 65];
    const int tid  = threadIdx.x;
    const int w    = __builtin_amdgcn_readfirstlane(tid >> 6);
    const int lane = tid & 63;
    const int node0 = blockIdx.x * 64;
    const int g = min(node0 + lane, NN - 1);
    const bool valid = (node0 + lane) < NN;

    float acc1[16];
    #pragma unroll
    for (int i = 0; i < 16; ++i) acc1[i] = 0.f;

    for (int j = 0; j < 2; ++j) {            // K-chunks of 128
        __syncthreads();
        for (int i = tid; i < 2048; i += 256) {
            int n = i / 32, k4 = i % 32;
            int gr = min(node0 + n, NN - 1);
            size_t a4 = (size_t)gr * 64 + j * 32 + k4;
            float4 xv = ((const float4*)xb)[a4];
            float4 lv = ((const float4*)LH)[a4];
            float* d = &xr[n * 129 + k4 * 4];
            d[0] = xv.x - fmaxf(lv.x, 0.f);
            d[1] = xv.y - fmaxf(lv.y, 0.f);
            d[2] = xv.z - fmaxf(lv.z, 0.f);
            d[3] = xv.w - fmaxf(lv.w, 0.f);
        }
        __syncthreads();
        for (int kt = 0; kt < 32; ++kt) {
            float xv0 = xr[lane * 129 + kt * 4 + 0];
            float xv1 = xr[lane * 129 + kt * 4 + 1];
            float xv2 = xr[lane * 129 + kt * 4 + 2];
            float xv3 = xr[lane * 129 + kt * 4 + 3];
            #pragma unroll
            for (int cc = 0; cc < 16; ++cc) {
                const int c = w * 16 + cc;
                const float* wr = Wo1 + (size_t)c * HID + j * 128 + kt * 4;
                acc1[cc] += xv0 * wr[0] + xv1 * wr[1] + xv2 * wr[2] + xv3 * wr[3];
            }
        }
    }
    __syncthreads();
    #pragma unroll
    for (int cc = 0; cc < 16; ++cc) {
        const int c = w * 16 + cc;
        t1s[lane * 65 + c] = fmaxf(acc1[cc] + bo1[c], 0.f);
    }
    __syncthreads();

    float acc2[4] = {0.f, 0.f, 0.f, 0.f};
    for (int kt = 0; kt < 8; ++kt) {
        float tv[8];
        #pragma unroll
        for (int i = 0; i < 8; ++i) tv[i] = t1s[lane * 65 + kt * 8 + i];
        #pragma unroll
        for (int jj = 0; jj < 4; ++jj) {
            const int c = w * 4 + jj;
            const float* wr = Wo2 + (size_t)c * MH + kt * 8;
            acc2[jj] += tv[0]*wr[0] + tv[1]*wr[1] + tv[2]*wr[2] + tv[3]*wr[3]
                      + tv[4]*wr[4] + tv[5]*wr[5] + tv[6]*wr[6] + tv[7]*wr[7];
        }
    }
    if (valid) {
        float4 v;
        v.x = acc2[0] + bo2[w*4+0];
        v.y = acc2[1] + bo2[w*4+1];
        v.z = acc2[2] + bo2[w*4+2];
        v.w = acc2[3] + bo2[w*4+3];
        *(float4*)(out + (size_t)g * OUT_D + w * 4) = v;
    }
}

// ---------------------------------------------------------------------------
// Workspace (floats): h | Fs | Ft | H(=As/Bs alias) | LH  = 21.76M = 87 MB
// ---------------------------------------------------------------------------
extern "C" void kernel_launch(void* const* d_in, const int* in_sizes, int n_in,
                              void* d_out, int out_size, void* d_ws, size_t ws_size,
                              hipStream_t stream)
{
    const float* x    = (const float*)d_in[0];
    const int*   ei   = (const int*)d_in[1];
    const float* Win1 = (const float*)d_in[2];
    const float* bin1 = (const float*)d_in[3];
    const float* Win2 = (const float*)d_in[4];
    const float* bin2 = (const float*)d_in[5];
    const float* Wm1  = (const float*)d_in[6];
    const float* bm1  = (const float*)d_in[7];
    const float* Wm2  = (const float*)d_in[8];
    const float* bm2  = (const float*)d_in[9];
    const float* Wd1  = (const float*)d_in[10];
    const float* Wd2  = (const float*)d_in[11];
    const float* Wo1  = (const float*)d_in[12];
    const float* bo1  = (const float*)d_in[13];
    const float* Wo2  = (const float*)d_in[14];
    const float* bo2  = (const float*)d_in[15];
    float* out = (float*)d_out;

    float* ws = (float*)d_ws;
    float* h  = ws;                          // N*256
    float* Fs = h  + (size_t)NN * HID;       // E*16
    float* Ft = Fs + (size_t)EE * 16;        // E*16
    float* H  = Ft + (size_t)EE * 16;        // N*256
    float* LH = H  + (size_t)NN * HID;       // N*256
    float* As = H;                           // aliases H (dead before H written)
    float* Bs = H  + (size_t)NN * MH;

    k_in_mlp<<<(NN + 63) / 64, 256, 0, stream>>>(x, Win1, bin1, Win2, bin2, Wm1, h, As, Bs);
    k_edge_msg<<<EE / 4, 256, 0, stream>>>(ei, As, Bs, bm1, Wm2, bm2, Fs, Ft);

    // layer 0
    hipMemsetAsync(LH, 0, (size_t)NN * HID * sizeof(float), stream);
    k_node_H<<<NN / 16, 256, 0, stream>>>(h, nullptr, Wd1, Wd2, H);
    k_edge_diff<<<EE / 4, 256, 0, stream>>>(ei, Fs, Ft, H, LH);

    // layer 1
    k_node_H<<<NN / 16, 256, 0, stream>>>(h, LH, Wd1 + 16, Wd2 + 4096, H);
    hipMemsetAsync(LH, 0, (size_t)NN * HID * sizeof(float), stream);
    k_edge_diff<<<EE / 4, 256, 0, stream>>>(ei, Fs, Ft, H, LH);

    k_out_mlp<<<(NN + 63) / 64, 256, 0, stream>>>(h, LH, Wo1, bo1, Wo2, bo2, out);
}

// Round 5
// 878.063 us; speedup vs baseline: 2.3198x; 1.4142x over previous
//
#include <hip/hip_runtime.h>

constexpr int NN   = 20000;
constexpr int EE   = 200000;
constexpr int IN_D = 500;
constexpr int HID  = 256;
constexpr int OUT_D= 16;
constexpr int MH   = 64;

// ===========================================================================
// CSR incidence build (rebuilt every launch; ws is re-poisoned each call).
// inc entry = edge*2 + is_dst.
// ===========================================================================
__global__ __launch_bounds__(256) void k_deg(const int* __restrict__ ei, int* __restrict__ deg)
{
    int e = blockIdx.x * 256 + threadIdx.x;
    if (e < EE) {
        atomicAdd(deg + ei[e], 1);
        atomicAdd(deg + ei[EE + e], 1);
    }
}

__global__ __launch_bounds__(256) void k_scan(const int* __restrict__ deg,
                                              int* __restrict__ off, int* __restrict__ cursor)
{
    __shared__ int part[256];
    __shared__ int base[256];
    const int tid = threadIdx.x;
    const int CH = (NN + 255) / 256;  // 79
    int s = 0;
    for (int i = 0; i < CH; ++i) { int n = tid * CH + i; if (n < NN) s += deg[n]; }
    part[tid] = s;
    __syncthreads();
    if (tid == 0) { int r = 0; for (int i = 0; i < 256; ++i) { base[i] = r; r += part[i]; } }
    __syncthreads();
    int r = base[tid];
    for (int i = 0; i < CH; ++i) {
        int n = tid * CH + i;
        if (n < NN) { off[n] = r; cursor[n] = r; r += deg[n]; }
    }
    if (tid == 255) off[NN] = r;   // = 2E
}

__global__ __launch_bounds__(256) void k_scatter(const int* __restrict__ ei,
                                                 int* __restrict__ cursor, int* __restrict__ inc)
{
    int e = blockIdx.x * 256 + threadIdx.x;
    if (e < EE) {
        int s = ei[e], d = ei[EE + e];
        int p = atomicAdd(cursor + s, 1); inc[p] = e * 2;
        p = atomicAdd(cursor + d, 1);     inc[p] = e * 2 + 1;
    }
}

// ===========================================================================
// k_in_mlp — lane = node, weights wave-uniform. 64 nodes/block. (unchanged)
// ===========================================================================
__global__ __launch_bounds__(256, 4) void k_in_mlp(
    const float* __restrict__ x,    const float* __restrict__ Win1, const float* __restrict__ bin1,
    const float* __restrict__ Win2, const float* __restrict__ bin2, const float* __restrict__ Wm1,
    float* __restrict__ h, float* __restrict__ As, float* __restrict__ Bs)
{
    __shared__ float xs[64 * 101];
    __shared__ float t1s[64 * 65];
    const int tid  = threadIdx.x;
    const int w    = __builtin_amdgcn_readfirstlane(tid >> 6);
    const int lane = tid & 63;
    const int node0 = blockIdx.x * 64;
    const int g = min(node0 + lane, NN - 1);
    const bool valid = (node0 + lane) < NN;

    float acc1[16];
    #pragma unroll
    for (int i = 0; i < 16; ++i) acc1[i] = 0.f;

    for (int j = 0; j < 5; ++j) {
        __syncthreads();
        for (int i = tid; i < 1600; i += 256) {
            int n = i / 25, k4 = i % 25;
            int gr = min(node0 + n, NN - 1);
            float4 v = ((const float4*)x)[(size_t)gr * 125 + j * 25 + k4];
            float* d = &xs[n * 101 + k4 * 4];
            d[0] = v.x; d[1] = v.y; d[2] = v.z; d[3] = v.w;
        }
        __syncthreads();
        for (int kt = 0; kt < 25; ++kt) {
            float xv0 = xs[lane * 101 + kt * 4 + 0];
            float xv1 = xs[lane * 101 + kt * 4 + 1];
            float xv2 = xs[lane * 101 + kt * 4 + 2];
            float xv3 = xs[lane * 101 + kt * 4 + 3];
            #pragma unroll
            for (int cc = 0; cc < 16; ++cc) {
                const int c = w * 16 + cc;
                const float* wr = Win1 + (size_t)c * IN_D + j * 100 + kt * 4;
                acc1[cc] += xv0 * wr[0] + xv1 * wr[1] + xv2 * wr[2] + xv3 * wr[3];
            }
        }
    }
    __syncthreads();
    #pragma unroll
    for (int cc = 0; cc < 16; ++cc) {
        const int c = w * 16 + cc;
        t1s[lane * 65 + c] = fmaxf(acc1[cc] + bin1[c], 0.f);
    }
    __syncthreads();

    float acc2[64];
    #pragma unroll
    for (int i = 0; i < 64; ++i) acc2[i] = 0.f;
    for (int kt = 0; kt < 8; ++kt) {
        float tv[8];
        #pragma unroll
        for (int i = 0; i < 8; ++i) tv[i] = t1s[lane * 65 + kt * 8 + i];
        #pragma unroll
        for (int cc = 0; cc < 64; ++cc) {
            const int c = w * 64 + cc;
            const float* wr = Win2 + (size_t)c * MH + kt * 8;
            acc2[cc] += tv[0]*wr[0] + tv[1]*wr[1] + tv[2]*wr[2] + tv[3]*wr[3]
                      + tv[4]*wr[4] + tv[5]*wr[5] + tv[6]*wr[6] + tv[7]*wr[7];
        }
    }
    if (valid) {
        float* hp = h + (size_t)g * HID + w * 64;
        #pragma unroll
        for (int c4 = 0; c4 < 16; ++c4) {
            float4 v;
            v.x = acc2[c4*4+0] + bin2[w*64 + c4*4+0];
            v.y = acc2[c4*4+1] + bin2[w*64 + c4*4+1];
            v.z = acc2[c4*4+2] + bin2[w*64 + c4*4+2];
            v.w = acc2[c4*4+3] + bin2[w*64 + c4*4+3];
            *(float4*)(hp + c4 * 4) = v;
        }
    }
    __threadfence_block();
    __syncthreads();

    float acc3[32];
    #pragma unroll
    for (int i = 0; i < 32; ++i) acc3[i] = 0.f;
    const float* hrow = h + (size_t)g * HID;
    for (int kt = 0; kt < 32; ++kt) {
        float4 a = *(const float4*)(hrow + kt * 8);
        float4 b = *(const float4*)(hrow + kt * 8 + 4);
        #pragma unroll
        for (int jj = 0; jj < 32; ++jj) {
            const int vc = w * 32 + jj;
            const int which = vc >> 6;
            const int c = vc & 63;
            const float* wr = Wm1 + (size_t)c * (2 * HID) + which * HID + kt * 8;
            acc3[jj] += a.x*wr[0] + a.y*wr[1] + a.z*wr[2] + a.w*wr[3]
                      + b.x*wr[4] + b.y*wr[5] + b.z*wr[6] + b.w*wr[7];
        }
    }
    if (valid) {
        float* dst = (w < 2) ? (As + (size_t)g * MH + w * 32)
                             : (Bs + (size_t)g * MH + (w - 2) * 32);
        #pragma unroll
        for (int j4 = 0; j4 < 8; ++j4) {
            float4 v;
            v.x = acc3[j4*4+0]; v.y = acc3[j4*4+1];
            v.z = acc3[j4*4+2]; v.w = acc3[j4*4+3];
            *(float4*)(dst + j4 * 4) = v;
        }
    }
}

// ===========================================================================
// k_edge_msg — per-edge messages; produce P = Fs.T@Ft (stored) and fold
// Q = Fs.T@Fs into M[src], R = Ft.T@Ft into M[dst] (atomic; 32/edge).
// Fs/Ft never hit global memory.
// ===========================================================================
__global__ __launch_bounds__(256) void k_edge_msg(
    const int* __restrict__ ei, const float* __restrict__ As, const float* __restrict__ Bs,
    const float* __restrict__ bm1, const float* __restrict__ Wm2, const float* __restrict__ bm2,
    float* __restrict__ P, float* __restrict__ M)
{
    __shared__ float plds[4][2][64];
    __shared__ float fls[4][2][16];
    const int tid = threadIdx.x;
    const int w = tid >> 6, t = tid & 63;
    const int e = blockIdx.x * 4 + w;
    const int src = ei[e], dst = ei[EE + e];
    float a_s = As[(size_t)src * MH + t], b_d = Bs[(size_t)dst * MH + t];
    float a_d = As[(size_t)dst * MH + t], b_s = Bs[(size_t)src * MH + t];
    float bm = bm1[t];
    plds[w][0][t] = fmaxf(a_s + b_d + bm, 0.f);   // pre-m1 (Fs)
    plds[w][1][t] = fmaxf(a_d + b_s + bm, 0.f);   // pre-m2 (Ft)
    __syncthreads();
    if (tid < 128) {
        int el = tid >> 5, rem = tid & 31, which = rem >> 4, j = rem & 15;
        float acc = bm2[j];
        const float4* wr = (const float4*)(Wm2 + (size_t)j * MH);
        const float4* p = (const float4*)(plds[el][which]);
        #pragma unroll
        for (int k = 0; k < MH / 4; ++k) {
            float4 wv = wr[k], pv = p[k];
            acc += pv.x * wv.x + pv.y * wv.y + pv.z * wv.z + pv.w * wv.w;
        }
        fls[el][which][j] = acc;
    }
    __syncthreads();
    if (tid < 64) {
        int el = tid >> 4, comp = tid & 15, j = comp >> 2, k = comp & 3;
        const float* f0 = fls[el][0];   // Fs rows: Fs[i][j] = f0[i*4+j]
        const float* f1 = fls[el][1];   // Ft
        float pp = 0.f, qq = 0.f, rr = 0.f;
        #pragma unroll
        for (int i = 0; i < 4; ++i) {
            float a = f0[i * 4 + j], b = f1[i * 4 + j];
            pp += a * f1[i * 4 + k];   // P[j,k]
            qq += a * f0[i * 4 + k];   // Q[j,k]
            rr += b * f1[i * 4 + k];   // R[j,k]
        }
        int eg = blockIdx.x * 4 + el;
        int s2 = ei[eg], d2 = ei[EE + eg];
        P[(size_t)eg * 16 + comp] = pp;
        atomicAdd(M + (size_t)s2 * 16 + comp, qq);
        atomicAdd(M + (size_t)d2 * 16 + comp, rr);
    }
}

// ===========================================================================
// k_node_H — H0 = (Wd1.T @ xb) @ Wd2.T per node (layer-0 input). Unchanged
// structure (wave=node-slot, lane=f), no LH here.
// ===========================================================================
__global__ __launch_bounds__(256) void k_node_H(
    const float* __restrict__ xb,
    const float* __restrict__ Wd1l, const float* __restrict__ Wd2l,
    float* __restrict__ H)
{
    __shared__ float wt[64][68];
    __shared__ float tl[4][4][64];
    const int tid = threadIdx.x;
    const int w = tid >> 6, t = tid & 63;

    for (int i = tid; i < 4096; i += 256) wt[i >> 6][i & 63] = Wd2l[i];
    float wd1[16];
    #pragma unroll
    for (int i = 0; i < 16; ++i) wd1[i] = Wd1l[i];
    __syncthreads();

    for (int rep = 0; rep < 4; ++rep) {
        const int n = blockIdx.x * 16 + w * 4 + rep;
        float xv[4];
        #pragma unroll
        for (int j = 0; j < 4; ++j) xv[j] = xb[(size_t)n * HID + j * 64 + t];
        #pragma unroll
        for (int i = 0; i < 4; ++i)
            tl[w][i][t] = wd1[0 + i] * xv[0] + wd1[4 + i] * xv[1] +
                          wd1[8 + i] * xv[2] + wd1[12 + i] * xv[3];
        __syncthreads();
        float a0 = 0, a1 = 0, a2 = 0, a3 = 0;
        #pragma unroll
        for (int f = 0; f < 64; f += 4) {
            float4 wv = *(const float4*)&wt[t][f];
            float4 t0 = *(const float4*)&tl[w][0][f];
            float4 t1 = *(const float4*)&tl[w][1][f];
            float4 t2 = *(const float4*)&tl[w][2][f];
            float4 t3 = *(const float4*)&tl[w][3][f];
            a0 += t0.x * wv.x + t0.y * wv.y + t0.z * wv.z + t0.w * wv.w;
            a1 += t1.x * wv.x + t1.y * wv.y + t1.z * wv.z + t1.w * wv.w;
            a2 += t2.x * wv.x + t2.y * wv.y + t2.z * wv.z + t2.w * wv.w;
            a3 += t3.x * wv.x + t3.y * wv.y + t3.z * wv.z + t3.w * wv.w;
        }
        __syncthreads();
        size_t base = (size_t)n * HID + t;
        H[base + 0 * 64] = a0;
        H[base + 1 * 64] = a1;
        H[base + 2 * 64] = a2;
        H[base + 3 * 64] = a3;
    }
}

// ===========================================================================
// k_node_sheaf<LAYER> — one wave per node (4 nodes/block), lane = f:
//   LH[n] = M[n]@H[n] − Σ_{src-inc} P_e@H[dst] − Σ_{dst-inc} P_e.T@H[src]
//   xb[n] −= relu(LH[n])  (in place)
//   LAYER==0: also Hout[n] = (Wd1.T @ xb[n]) @ Wd2.T  (next layer's H)
// No atomics; LH never materialized.
// ===========================================================================
template<int LAYER>
__global__ __launch_bounds__(256) void k_node_sheaf(
    const int* __restrict__ ei, const int* __restrict__ off, const int* __restrict__ inc,
    const float* __restrict__ P, const float* __restrict__ M,
    const float* __restrict__ Hin, float* __restrict__ h, float* __restrict__ Hout,
    const float* __restrict__ Wd1l, const float* __restrict__ Wd2l)
{
    __shared__ float wt[64][68];
    __shared__ float tl[4][4][64];
    const int tid = threadIdx.x;
    const int w = tid >> 6, t = tid & 63;

    if (LAYER == 0) {
        for (int i = tid; i < 4096; i += 256) wt[i >> 6][i & 63] = Wd2l[i];
    }
    float wd1[16];
    if (LAYER == 0) {
        #pragma unroll
        for (int i = 0; i < 16; ++i) wd1[i] = Wd1l[i];
        __syncthreads();
    }

    const int n = blockIdx.x * 4 + w;
    float Hn[4];
    #pragma unroll
    for (int k = 0; k < 4; ++k) Hn[k] = Hin[(size_t)n * HID + k * 64 + t];

    float Mn[16];
    #pragma unroll
    for (int c = 0; c < 16; ++c) Mn[c] = M[(size_t)n * 16 + c];

    float acc[4];
    #pragma unroll
    for (int j = 0; j < 4; ++j)
        acc[j] = Mn[j*4+0]*Hn[0] + Mn[j*4+1]*Hn[1] + Mn[j*4+2]*Hn[2] + Mn[j*4+3]*Hn[3];

    const int p0 = off[n], p1 = off[n + 1];
    for (int p = p0; p < p1; ++p) {
        int v = inc[p];
        int e = v >> 1, isdst = v & 1;
        int other = isdst ? ei[e] : ei[EE + e];
        float Ho[4];
        #pragma unroll
        for (int k = 0; k < 4; ++k) Ho[k] = Hin[(size_t)other * HID + k * 64 + t];
        const float* Pe = P + (size_t)e * 16;
        if (!isdst) {
            #pragma unroll
            for (int j = 0; j < 4; ++j)
                acc[j] -= Pe[j*4+0]*Ho[0] + Pe[j*4+1]*Ho[1] + Pe[j*4+2]*Ho[2] + Pe[j*4+3]*Ho[3];
        } else {
            #pragma unroll
            for (int j = 0; j < 4; ++j)
                acc[j] -= Pe[0*4+j]*Ho[0] + Pe[1*4+j]*Ho[1] + Pe[2*4+j]*Ho[2] + Pe[3*4+j]*Ho[3];
        }
    }

    float xv[4];
    #pragma unroll
    for (int j = 0; j < 4; ++j) {
        size_t idx = (size_t)n * HID + j * 64 + t;
        float vv = h[idx] - fmaxf(acc[j], 0.f);
        h[idx] = vv;
        xv[j] = vv;
    }

    if (LAYER == 0) {
        #pragma unroll
        for (int i = 0; i < 4; ++i)
            tl[w][i][t] = wd1[0 + i] * xv[0] + wd1[4 + i] * xv[1] +
                          wd1[8 + i] * xv[2] + wd1[12 + i] * xv[3];
        __syncthreads();
        float a0 = 0, a1 = 0, a2 = 0, a3 = 0;
        #pragma unroll
        for (int f = 0; f < 64; f += 4) {
            float4 wv = *(const float4*)&wt[t][f];
            float4 t0 = *(const float4*)&tl[w][0][f];
            float4 t1 = *(const float4*)&tl[w][1][f];
            float4 t2 = *(const float4*)&tl[w][2][f];
            float4 t3 = *(const float4*)&tl[w][3][f];
            a0 += t0.x * wv.x + t0.y * wv.y + t0.z * wv.z + t0.w * wv.w;
            a1 += t1.x * wv.x + t1.y * wv.y + t1.z * wv.z + t1.w * wv.w;
            a2 += t2.x * wv.x + t2.y * wv.y + t2.z * wv.z + t2.w * wv.w;
            a3 += t3.x * wv.x + t3.y * wv.y + t3.z * wv.z + t3.w * wv.w;
        }
        size_t base = (size_t)n * HID + t;
        Hout[base + 0 * 64] = a0;
        Hout[base + 1 * 64] = a1;
        Hout[base + 2 * 64] = a2;
        Hout[base + 3 * 64] = a3;
    }
}

// ===========================================================================
// k_out_mlp — lane = node; final xb already in h (no LH subtraction).
// ===========================================================================
__global__ __launch_bounds__(256, 4) void k_out_mlp(
    const float* __restrict__ xb,
    const float* __restrict__ Wo1, const float* __restrict__ bo1,
    const float* __restrict__ Wo2, const float* __restrict__ bo2,
    float* __restrict__ out)
{
    __shared__ float xr[64 * 129];
    __shared__ float t1s[64 * 65];
    const int tid  = threadIdx.x;
    const int w    = __builtin_amdgcn_readfirstlane(tid >> 6);
    const int lane = tid & 63;
    const int node0 = blockIdx.x * 64;
    const int g = min(node0 + lane, NN - 1);
    const bool valid = (node0 + lane) < NN;

    float acc1[16];
    #pragma unroll
    for (int i = 0; i < 16; ++i) acc1[i] = 0.f;

    for (int j = 0; j < 2; ++j) {
        __syncthreads();
        for (int i = tid; i < 2048; i += 256) {
            int n = i / 32, k4 = i % 32;
            int gr = min(node0 + n, NN - 1);
            float4 xv = ((const float4*)xb)[(size_t)gr * 64 + j * 32 + k4];
            float* d = &xr[n * 129 + k4 * 4];
            d[0] = xv.x; d[1] = xv.y; d[2] = xv.z; d[3] = xv.w;
        }
        __syncthreads();
        for (int kt = 0; kt < 32; ++kt) {
            float xv0 = xr[lane * 129 + kt * 4 + 0];
            float xv1 = xr[lane * 129 + kt * 4 + 1];
            float xv2 = xr[lane * 129 + kt * 4 + 2];
            float xv3 = xr[lane * 129 + kt * 4 + 3];
            #pragma unroll
            for (int cc = 0; cc < 16; ++cc) {
                const int c = w * 16 + cc;
                const float* wr = Wo1 + (size_t)c * HID + j * 128 + kt * 4;
                acc1[cc] += xv0 * wr[0] + xv1 * wr[1] + xv2 * wr[2] + xv3 * wr[3];
            }
        }
    }
    __syncthreads();
    #pragma unroll
    for (int cc = 0; cc < 16; ++cc) {
        const int c = w * 16 + cc;
        t1s[lane * 65 + c] = fmaxf(acc1[cc] + bo1[c], 0.f);
    }
    __syncthreads();

    float acc2[4] = {0.f, 0.f, 0.f, 0.f};
    for (int kt = 0; kt < 8; ++kt) {
        float tv[8];
        #pragma unroll
        for (int i = 0; i < 8; ++i) tv[i] = t1s[lane * 65 + kt * 8 + i];
        #pragma unroll
        for (int jj = 0; jj < 4; ++jj) {
            const int c = w * 4 + jj;
            const float* wr = Wo2 + (size_t)c * MH + kt * 8;
            acc2[jj] += tv[0]*wr[0] + tv[1]*wr[1] + tv[2]*wr[2] + tv[3]*wr[3]
                      + tv[4]*wr[4] + tv[5]*wr[5] + tv[6]*wr[6] + tv[7]*wr[7];
        }
    }
    if (valid) {
        float4 v;
        v.x = acc2[0] + bo2[w*4+0];
        v.y = acc2[1] + bo2[w*4+1];
        v.z = acc2[2] + bo2[w*4+2];
        v.w = acc2[3] + bo2[w*4+3];
        *(float4*)(out + (size_t)g * OUT_D + w * 4) = v;
    }
}

// ---------------------------------------------------------------------------
// Workspace (floats):
//   h 5.12M | As 1.28M | Bs 1.28M | H0 5.12M | H1 5.12M | P 3.2M | M 0.32M
//   ints: deg 20000 | off 20001 | cursor 20000 | inc 400000
// total ≈ 21.9M × 4B ≈ 87.6 MB
// ---------------------------------------------------------------------------
extern "C" void kernel_launch(void* const* d_in, const int* in_sizes, int n_in,
                              void* d_out, int out_size, void* d_ws, size_t ws_size,
                              hipStream_t stream)
{
    const float* x    = (const float*)d_in[0];
    const int*   ei   = (const int*)d_in[1];
    const float* Win1 = (const float*)d_in[2];
    const float* bin1 = (const float*)d_in[3];
    const float* Win2 = (const float*)d_in[4];
    const float* bin2 = (const float*)d_in[5];
    const float* Wm1  = (const float*)d_in[6];
    const float* bm1  = (const float*)d_in[7];
    const float* Wm2  = (const float*)d_in[8];
    const float* bm2  = (const float*)d_in[9];
    const float* Wd1  = (const float*)d_in[10];
    const float* Wd2  = (const float*)d_in[11];
    const float* Wo1  = (const float*)d_in[12];
    const float* bo1  = (const float*)d_in[13];
    const float* Wo2  = (const float*)d_in[14];
    const float* bo2  = (const float*)d_in[15];
    float* out = (float*)d_out;

    float* ws = (float*)d_ws;
    float* h  = ws;                            // N*256
    float* As = h  + (size_t)NN * HID;         // N*64
    float* Bs = As + (size_t)NN * MH;          // N*64
    float* H0 = Bs + (size_t)NN * MH;          // N*256
    float* H1 = H0 + (size_t)NN * HID;         // N*256
    float* P  = H1 + (size_t)NN * HID;         // E*16
    float* M  = P  + (size_t)EE * 16;          // N*16
    int* deg    = (int*)(M + (size_t)NN * 16); // N
    int* off    = deg + NN;                    // N+1
    int* cursor = off + NN + 1;                // N
    int* inc    = cursor + NN;                 // 2E

    // CSR build + M zero
    hipMemsetAsync(deg, 0, NN * sizeof(int), stream);
    hipMemsetAsync(M, 0, (size_t)NN * 16 * sizeof(float), stream);
    k_deg<<<(EE + 255) / 256, 256, 0, stream>>>(ei, deg);
    k_scan<<<1, 256, 0, stream>>>(deg, off, cursor);
    k_scatter<<<(EE + 255) / 256, 256, 0, stream>>>(ei, cursor, inc);

    // node MLP + per-edge P/Q/R
    k_in_mlp<<<(NN + 63) / 64, 256, 0, stream>>>(x, Win1, bin1, Win2, bin2, Wm1, h, As, Bs);
    k_edge_msg<<<EE / 4, 256, 0, stream>>>(ei, As, Bs, bm1, Wm2, bm2, P, M);

    // diffusion
    k_node_H<<<NN / 16, 256, 0, stream>>>(h, Wd1, Wd2, H0);
    k_node_sheaf<0><<<NN / 4, 256, 0, stream>>>(ei, off, inc, P, M, H0, h, H1,
                                                Wd1 + 16, Wd2 + 4096);
    k_node_sheaf<1><<<NN / 4, 256, 0, stream>>>(ei, off, inc, P, M, H1, h, nullptr,
                                                nullptr, nullptr);

    k_out_mlp<<<(NN + 63) / 64, 256, 0, stream>>>(h, Wo1, bo1, Wo2, bo2, out);
}

// Round 6
// 760.551 us; speedup vs baseline: 2.6782x; 1.1545x over previous
//
#include <hip/hip_runtime.h>

constexpr int NN   = 20000;
constexpr int EE   = 200000;
constexpr int IN_D = 500;
constexpr int HID  = 256;
constexpr int OUT_D= 16;
constexpr int MH   = 64;

// ===========================================================================
// CSR incidence build. inc entry = edge*2 + is_dst.
// ===========================================================================
__global__ __launch_bounds__(256) void k_deg(const int* __restrict__ ei, int* __restrict__ deg)
{
    int e = blockIdx.x * 256 + threadIdx.x;
    if (e < EE) {
        atomicAdd(deg + ei[e], 1);
        atomicAdd(deg + ei[EE + e], 1);
    }
}

__global__ __launch_bounds__(256) void k_scan(const int* __restrict__ deg,
                                              int* __restrict__ off, int* __restrict__ cursor)
{
    __shared__ int part[256];
    __shared__ int base[256];
    const int tid = threadIdx.x;
    const int CH = (NN + 255) / 256;
    int s = 0;
    for (int i = 0; i < CH; ++i) { int n = tid * CH + i; if (n < NN) s += deg[n]; }
    part[tid] = s;
    __syncthreads();
    if (tid == 0) { int r = 0; for (int i = 0; i < 256; ++i) { base[i] = r; r += part[i]; } }
    __syncthreads();
    int r = base[tid];
    for (int i = 0; i < CH; ++i) {
        int n = tid * CH + i;
        if (n < NN) { off[n] = r; cursor[n] = r; r += deg[n]; }
    }
    if (tid == 255) off[NN] = r;
}

__global__ __launch_bounds__(256) void k_scatter(const int* __restrict__ ei,
                                                 int* __restrict__ cursor, int* __restrict__ inc)
{
    int e = blockIdx.x * 256 + threadIdx.x;
    if (e < EE) {
        int s = ei[e], d = ei[EE + e];
        int p = atomicAdd(cursor + s, 1); inc[p] = e * 2;
        p = atomicAdd(cursor + d, 1);     inc[p] = e * 2 + 1;
    }
}

// ===========================================================================
// k_mlp1: t1 = relu(x @ Win1.T + bin1).  grid (N/64, 4); block = 16 c's.
// lane = node; weights wave-uniform (scalar loads).
// ===========================================================================
__global__ __launch_bounds__(256, 4) void k_mlp1(
    const float* __restrict__ x, const float* __restrict__ Win1, const float* __restrict__ bin1,
    float* __restrict__ t1)
{
    __shared__ float xs[64 * 101];   // 25.9 KB
    const int tid  = threadIdx.x;
    const int w    = __builtin_amdgcn_readfirstlane(tid >> 6);
    const int lane = tid & 63;
    const int node0 = blockIdx.x * 64;
    const int cbase = blockIdx.y * 16 + w * 4;
    const int g = min(node0 + lane, NN - 1);
    const bool valid = (node0 + lane) < NN;

    float acc[4] = {0.f, 0.f, 0.f, 0.f};

    for (int j = 0; j < 5; ++j) {            // K-chunks of 100
        __syncthreads();
        for (int i = tid; i < 1600; i += 256) {
            int n = i / 25, k4 = i % 25;
            int gr = min(node0 + n, NN - 1);
            float4 v = ((const float4*)x)[(size_t)gr * 125 + j * 25 + k4];
            float* d = &xs[n * 101 + k4 * 4];
            d[0] = v.x; d[1] = v.y; d[2] = v.z; d[3] = v.w;
        }
        __syncthreads();
        for (int kt = 0; kt < 25; ++kt) {
            float x0 = xs[lane * 101 + kt * 4 + 0];
            float x1 = xs[lane * 101 + kt * 4 + 1];
            float x2 = xs[lane * 101 + kt * 4 + 2];
            float x3 = xs[lane * 101 + kt * 4 + 3];
            #pragma unroll
            for (int cc = 0; cc < 4; ++cc) {
                const float* wr = Win1 + (size_t)(cbase + cc) * IN_D + j * 100 + kt * 4;
                acc[cc] += x0 * wr[0] + x1 * wr[1] + x2 * wr[2] + x3 * wr[3];
            }
        }
    }
    if (valid) {
        float4 v;
        v.x = fmaxf(acc[0] + bin1[cbase + 0], 0.f);
        v.y = fmaxf(acc[1] + bin1[cbase + 1], 0.f);
        v.z = fmaxf(acc[2] + bin1[cbase + 2], 0.f);
        v.w = fmaxf(acc[3] + bin1[cbase + 3], 0.f);
        *(float4*)(t1 + (size_t)g * MH + cbase) = v;
    }
}

// ===========================================================================
// k_mlp2: h = t1 @ Win2.T + bin2.  grid (N/64, 4); block = 64 c's (16/wave).
// ===========================================================================
__global__ __launch_bounds__(256, 4) void k_mlp2(
    const float* __restrict__ t1, const float* __restrict__ Win2, const float* __restrict__ bin2,
    float* __restrict__ h)
{
    __shared__ float ts[64 * 65];    // 16.6 KB
    const int tid  = threadIdx.x;
    const int w    = __builtin_amdgcn_readfirstlane(tid >> 6);
    const int lane = tid & 63;
    const int node0 = blockIdx.x * 64;
    const int cbase = blockIdx.y * 64 + w * 16;
    const int g = min(node0 + lane, NN - 1);
    const bool valid = (node0 + lane) < NN;

    for (int i = tid; i < 1024; i += 256) {
        int n = i >> 4, k4 = i & 15;
        int gr = min(node0 + n, NN - 1);
        float4 v = ((const float4*)t1)[(size_t)gr * 16 + k4];
        float* d = &ts[n * 65 + k4 * 4];
        d[0] = v.x; d[1] = v.y; d[2] = v.z; d[3] = v.w;
    }
    __syncthreads();

    float acc[16];
    #pragma unroll
    for (int i = 0; i < 16; ++i) acc[i] = 0.f;
    for (int kt = 0; kt < 8; ++kt) {
        float tv[8];
        #pragma unroll
        for (int i = 0; i < 8; ++i) tv[i] = ts[lane * 65 + kt * 8 + i];
        #pragma unroll
        for (int cc = 0; cc < 16; ++cc) {
            const float* wr = Win2 + (size_t)(cbase + cc) * MH + kt * 8;
            acc[cc] += tv[0]*wr[0] + tv[1]*wr[1] + tv[2]*wr[2] + tv[3]*wr[3]
                     + tv[4]*wr[4] + tv[5]*wr[5] + tv[6]*wr[6] + tv[7]*wr[7];
        }
    }
    if (valid) {
        float* hp = h + (size_t)g * HID + cbase;
        #pragma unroll
        for (int c4 = 0; c4 < 4; ++c4) {
            float4 v;
            v.x = acc[c4*4+0] + bin2[cbase + c4*4+0];
            v.y = acc[c4*4+1] + bin2[cbase + c4*4+1];
            v.z = acc[c4*4+2] + bin2[cbase + c4*4+2];
            v.w = acc[c4*4+3] + bin2[cbase + c4*4+3];
            *(float4*)(hp + c4 * 4) = v;
        }
    }
}

// ===========================================================================
// k_mlp3: As = h @ Wa.T, Bs = h @ Wb.T.  grid (N/64, 4); block = 32 vc (8/wave).
// vc in [0,128): which = vc>>6 (A/B), c = vc&63.  which uniform per wave-range.
// ===========================================================================
__global__ __launch_bounds__(256, 4) void k_mlp3(
    const float* __restrict__ h, const float* __restrict__ Wm1,
    float* __restrict__ As, float* __restrict__ Bs)
{
    __shared__ float hsm[64 * 65];   // 16.6 KB (one 64-k chunk of h)
    const int tid  = threadIdx.x;
    const int w    = __builtin_amdgcn_readfirstlane(tid >> 6);
    const int lane = tid & 63;
    const int node0 = blockIdx.x * 64;
    const int vcb = blockIdx.y * 32 + w * 8;
    const int which = vcb >> 6;
    const int cb = vcb & 63;
    const int g = min(node0 + lane, NN - 1);
    const bool valid = (node0 + lane) < NN;

    float acc[8];
    #pragma unroll
    for (int i = 0; i < 8; ++i) acc[i] = 0.f;

    for (int ch = 0; ch < 4; ++ch) {         // 64-k chunks of HID
        __syncthreads();
        for (int i = tid; i < 1024; i += 256) {
            int n = i >> 4, k4 = i & 15;
            int gr = min(node0 + n, NN - 1);
            float4 v = ((const float4*)h)[(size_t)gr * 64 + ch * 16 + k4];
            float* d = &hsm[n * 65 + k4 * 4];
            d[0] = v.x; d[1] = v.y; d[2] = v.z; d[3] = v.w;
        }
        __syncthreads();
        for (int kt = 0; kt < 8; ++kt) {
            float tv[8];
            #pragma unroll
            for (int i = 0; i < 8; ++i) tv[i] = hsm[lane * 65 + kt * 8 + i];
            #pragma unroll
            for (int jj = 0; jj < 8; ++jj) {
                const float* wr = Wm1 + (size_t)(cb + jj) * (2 * HID) + which * HID
                                + ch * 64 + kt * 8;
                acc[jj] += tv[0]*wr[0] + tv[1]*wr[1] + tv[2]*wr[2] + tv[3]*wr[3]
                         + tv[4]*wr[4] + tv[5]*wr[5] + tv[6]*wr[6] + tv[7]*wr[7];
            }
        }
    }
    if (valid) {
        float* dst = (which ? Bs : As) + (size_t)g * MH + cb;
        float4 v0, v1;
        v0.x = acc[0]; v0.y = acc[1]; v0.z = acc[2]; v0.w = acc[3];
        v1.x = acc[4]; v1.y = acc[5]; v1.z = acc[6]; v1.w = acc[7];
        *(float4*)(dst + 0) = v0;
        *(float4*)(dst + 4) = v1;
    }
}

// ===========================================================================
// k_edge_msg — per-edge P = Fs.T@Ft; fold Q into M[src], R into M[dst].
// ===========================================================================
__global__ __launch_bounds__(256) void k_edge_msg(
    const int* __restrict__ ei, const float* __restrict__ As, const float* __restrict__ Bs,
    const float* __restrict__ bm1, const float* __restrict__ Wm2, const float* __restrict__ bm2,
    float* __restrict__ P, float* __restrict__ M)
{
    __shared__ float plds[4][2][64];
    __shared__ float fls[4][2][16];
    const int tid = threadIdx.x;
    const int w = tid >> 6, t = tid & 63;
    const int e = blockIdx.x * 4 + w;
    const int src = ei[e], dst = ei[EE + e];
    float a_s = As[(size_t)src * MH + t], b_d = Bs[(size_t)dst * MH + t];
    float a_d = As[(size_t)dst * MH + t], b_s = Bs[(size_t)src * MH + t];
    float bm = bm1[t];
    plds[w][0][t] = fmaxf(a_s + b_d + bm, 0.f);
    plds[w][1][t] = fmaxf(a_d + b_s + bm, 0.f);
    __syncthreads();
    if (tid < 128) {
        int el = tid >> 5, rem = tid & 31, which = rem >> 4, j = rem & 15;
        float acc = bm2[j];
        const float4* wr = (const float4*)(Wm2 + (size_t)j * MH);
        const float4* p = (const float4*)(plds[el][which]);
        #pragma unroll
        for (int k = 0; k < MH / 4; ++k) {
            float4 wv = wr[k], pv = p[k];
            acc += pv.x * wv.x + pv.y * wv.y + pv.z * wv.z + pv.w * wv.w;
        }
        fls[el][which][j] = acc;
    }
    __syncthreads();
    if (tid < 64) {
        int el = tid >> 4, comp = tid & 15, j = comp >> 2, k = comp & 3;
        const float* f0 = fls[el][0];
        const float* f1 = fls[el][1];
        float pp = 0.f, qq = 0.f, rr = 0.f;
        #pragma unroll
        for (int i = 0; i < 4; ++i) {
            float a = f0[i * 4 + j], b = f1[i * 4 + j];
            pp += a * f1[i * 4 + k];
            qq += a * f0[i * 4 + k];
            rr += b * f1[i * 4 + k];
        }
        int eg = blockIdx.x * 4 + el;
        int s2 = ei[eg], d2 = ei[EE + eg];
        P[(size_t)eg * 16 + comp] = pp;
        atomicAdd(M + (size_t)s2 * 16 + comp, qq);
        atomicAdd(M + (size_t)d2 * 16 + comp, rr);
    }
}

// ===========================================================================
// k_node_H — H0 = (Wd1.T @ xb) @ Wd2.T per node.
// ===========================================================================
__global__ __launch_bounds__(256) void k_node_H(
    const float* __restrict__ xb,
    const float* __restrict__ Wd1l, const float* __restrict__ Wd2l,
    float* __restrict__ H)
{
    __shared__ float wt[64][68];
    __shared__ float tl[4][4][64];
    const int tid = threadIdx.x;
    const int w = tid >> 6, t = tid & 63;

    for (int i = tid; i < 4096; i += 256) wt[i >> 6][i & 63] = Wd2l[i];
    float wd1[16];
    #pragma unroll
    for (int i = 0; i < 16; ++i) wd1[i] = Wd1l[i];
    __syncthreads();

    for (int rep = 0; rep < 4; ++rep) {
        const int n = blockIdx.x * 16 + w * 4 + rep;
        float xv[4];
        #pragma unroll
        for (int j = 0; j < 4; ++j) xv[j] = xb[(size_t)n * HID + j * 64 + t];
        #pragma unroll
        for (int i = 0; i < 4; ++i)
            tl[w][i][t] = wd1[0 + i] * xv[0] + wd1[4 + i] * xv[1] +
                          wd1[8 + i] * xv[2] + wd1[12 + i] * xv[3];
        __syncthreads();
        float a0 = 0, a1 = 0, a2 = 0, a3 = 0;
        #pragma unroll
        for (int f = 0; f < 64; f += 4) {
            float4 wv = *(const float4*)&wt[t][f];
            float4 t0 = *(const float4*)&tl[w][0][f];
            float4 t1 = *(const float4*)&tl[w][1][f];
            float4 t2 = *(const float4*)&tl[w][2][f];
            float4 t3 = *(const float4*)&tl[w][3][f];
            a0 += t0.x * wv.x + t0.y * wv.y + t0.z * wv.z + t0.w * wv.w;
            a1 += t1.x * wv.x + t1.y * wv.y + t1.z * wv.z + t1.w * wv.w;
            a2 += t2.x * wv.x + t2.y * wv.y + t2.z * wv.z + t2.w * wv.w;
            a3 += t3.x * wv.x + t3.y * wv.y + t3.z * wv.z + t3.w * wv.w;
        }
        __syncthreads();
        size_t base = (size_t)n * HID + t;
        H[base + 0 * 64] = a0;
        H[base + 1 * 64] = a1;
        H[base + 2 * 64] = a2;
        H[base + 3 * 64] = a3;
    }
}

// ===========================================================================
// k_node_sheaf<LAYER> — LH[n] via CSR gather (no atomics); xb update in place;
// LAYER==0 also produces next-layer H.
// ===========================================================================
template<int LAYER>
__global__ __launch_bounds__(256) void k_node_sheaf(
    const int* __restrict__ ei, const int* __restrict__ off, const int* __restrict__ inc,
    const float* __restrict__ P, const float* __restrict__ M,
    const float* __restrict__ Hin, float* __restrict__ h, float* __restrict__ Hout,
    const float* __restrict__ Wd1l, const float* __restrict__ Wd2l)
{
    __shared__ float wt[64][68];
    __shared__ float tl[4][4][64];
    const int tid = threadIdx.x;
    const int w = tid >> 6, t = tid & 63;

    if (LAYER == 0) {
        for (int i = tid; i < 4096; i += 256) wt[i >> 6][i & 63] = Wd2l[i];
    }
    float wd1[16];
    if (LAYER == 0) {
        #pragma unroll
        for (int i = 0; i < 16; ++i) wd1[i] = Wd1l[i];
        __syncthreads();
    }

    const int n = blockIdx.x * 4 + w;
    float Hn[4];
    #pragma unroll
    for (int k = 0; k < 4; ++k) Hn[k] = Hin[(size_t)n * HID + k * 64 + t];

    float Mn[16];
    #pragma unroll
    for (int c = 0; c < 16; ++c) Mn[c] = M[(size_t)n * 16 + c];

    float acc[4];
    #pragma unroll
    for (int j = 0; j < 4; ++j)
        acc[j] = Mn[j*4+0]*Hn[0] + Mn[j*4+1]*Hn[1] + Mn[j*4+2]*Hn[2] + Mn[j*4+3]*Hn[3];

    const int p0 = off[n], p1 = off[n + 1];
    for (int p = p0; p < p1; ++p) {
        int v = inc[p];
        int e = v >> 1, isdst = v & 1;
        int other = isdst ? ei[e] : ei[EE + e];
        float Ho[4];
        #pragma unroll
        for (int k = 0; k < 4; ++k) Ho[k] = Hin[(size_t)other * HID + k * 64 + t];
        const float* Pe = P + (size_t)e * 16;
        if (!isdst) {
            #pragma unroll
            for (int j = 0; j < 4; ++j)
                acc[j] -= Pe[j*4+0]*Ho[0] + Pe[j*4+1]*Ho[1] + Pe[j*4+2]*Ho[2] + Pe[j*4+3]*Ho[3];
        } else {
            #pragma unroll
            for (int j = 0; j < 4; ++j)
                acc[j] -= Pe[0*4+j]*Ho[0] + Pe[1*4+j]*Ho[1] + Pe[2*4+j]*Ho[2] + Pe[3*4+j]*Ho[3];
        }
    }

    float xv[4];
    #pragma unroll
    for (int j = 0; j < 4; ++j) {
        size_t idx = (size_t)n * HID + j * 64 + t;
        float vv = h[idx] - fmaxf(acc[j], 0.f);
        h[idx] = vv;
        xv[j] = vv;
    }

    if (LAYER == 0) {
        #pragma unroll
        for (int i = 0; i < 4; ++i)
            tl[w][i][t] = wd1[0 + i] * xv[0] + wd1[4 + i] * xv[1] +
                          wd1[8 + i] * xv[2] + wd1[12 + i] * xv[3];
        __syncthreads();
        float a0 = 0, a1 = 0, a2 = 0, a3 = 0;
        #pragma unroll
        for (int f = 0; f < 64; f += 4) {
            float4 wv = *(const float4*)&wt[t][f];
            float4 t0 = *(const float4*)&tl[w][0][f];
            float4 t1 = *(const float4*)&tl[w][1][f];
            float4 t2 = *(const float4*)&tl[w][2][f];
            float4 t3 = *(const float4*)&tl[w][3][f];
            a0 += t0.x * wv.x + t0.y * wv.y + t0.z * wv.z + t0.w * wv.w;
            a1 += t1.x * wv.x + t1.y * wv.y + t1.z * wv.z + t1.w * wv.w;
            a2 += t2.x * wv.x + t2.y * wv.y + t2.z * wv.z + t2.w * wv.w;
            a3 += t3.x * wv.x + t3.y * wv.y + t3.z * wv.z + t3.w * wv.w;
        }
        size_t base = (size_t)n * HID + t;
        Hout[base + 0 * 64] = a0;
        Hout[base + 1 * 64] = a1;
        Hout[base + 2 * 64] = a2;
        Hout[base + 3 * 64] = a3;
    }
}

// ===========================================================================
// k_out1: t1o = relu(xb @ Wo1.T + bo1).  grid (N/64, 4); block = 16 c's.
// ===========================================================================
__global__ __launch_bounds__(256, 4) void k_out1(
    const float* __restrict__ xb, const float* __restrict__ Wo1, const float* __restrict__ bo1,
    float* __restrict__ t1o)
{
    __shared__ float xr[64 * 129];   // 33 KB
    const int tid  = threadIdx.x;
    const int w    = __builtin_amdgcn_readfirstlane(tid >> 6);
    const int lane = tid & 63;
    const int node0 = blockIdx.x * 64;
    const int cbase = blockIdx.y * 16 + w * 4;
    const int g = min(node0 + lane, NN - 1);
    const bool valid = (node0 + lane) < NN;

    float acc[4] = {0.f, 0.f, 0.f, 0.f};

    for (int j = 0; j < 2; ++j) {            // 128-k chunks
        __syncthreads();
        for (int i = tid; i < 2048; i += 256) {
            int n = i >> 5, k4 = i & 31;
            int gr = min(node0 + n, NN - 1);
            float4 v = ((const float4*)xb)[(size_t)gr * 64 + j * 32 + k4];
            float* d = &xr[n * 129 + k4 * 4];
            d[0] = v.x; d[1] = v.y; d[2] = v.z; d[3] = v.w;
        }
        __syncthreads();
        for (int kt = 0; kt < 32; ++kt) {
            float x0 = xr[lane * 129 + kt * 4 + 0];
            float x1 = xr[lane * 129 + kt * 4 + 1];
            float x2 = xr[lane * 129 + kt * 4 + 2];
            float x3 = xr[lane * 129 + kt * 4 + 3];
            #pragma unroll
            for (int cc = 0; cc < 4; ++cc) {
                const float* wr = Wo1 + (size_t)(cbase + cc) * HID + j * 128 + kt * 4;
                acc[cc] += x0 * wr[0] + x1 * wr[1] + x2 * wr[2] + x3 * wr[3];
            }
        }
    }
    if (valid) {
        float4 v;
        v.x = fmaxf(acc[0] + bo1[cbase + 0], 0.f);
        v.y = fmaxf(acc[1] + bo1[cbase + 1], 0.f);
        v.z = fmaxf(acc[2] + bo1[cbase + 2], 0.f);
        v.w = fmaxf(acc[3] + bo1[cbase + 3], 0.f);
        *(float4*)(t1o + (size_t)g * MH + cbase) = v;
    }
}

// ===========================================================================
// k_out2: out = t1o @ Wo2.T + bo2.  grid N/64; lane = node, 16 outputs each.
// ===========================================================================
__global__ __launch_bounds__(256, 4) void k_out2(
    const float* __restrict__ t1o, const float* __restrict__ Wo2, const float* __restrict__ bo2,
    float* __restrict__ out)
{
    __shared__ float ts[64 * 65];
    const int tid  = threadIdx.x;
    const int lane = tid & 63;
    const int node0 = blockIdx.x * 64;
    const int g = min(node0 + lane, NN - 1);
    const bool valid = (node0 + lane) < NN;

    for (int i = tid; i < 1024; i += 256) {
        int n = i >> 4, k4 = i & 15;
        int gr = min(node0 + n, NN - 1);
        float4 v = ((const float4*)t1o)[(size_t)gr * 16 + k4];
        float* d = &ts[n * 65 + k4 * 4];
        d[0] = v.x; d[1] = v.y; d[2] = v.z; d[3] = v.w;
    }
    __syncthreads();

    float acc[16];
    #pragma unroll
    for (int i = 0; i < 16; ++i) acc[i] = 0.f;
    for (int kt = 0; kt < 8; ++kt) {
        float tv[8];
        #pragma unroll
        for (int i = 0; i < 8; ++i) tv[i] = ts[lane * 65 + kt * 8 + i];
        #pragma unroll
        for (int jj = 0; jj < 16; ++jj) {
            const float* wr = Wo2 + (size_t)jj * MH + kt * 8;
            acc[jj] += tv[0]*wr[0] + tv[1]*wr[1] + tv[2]*wr[2] + tv[3]*wr[3]
                     + tv[4]*wr[4] + tv[5]*wr[5] + tv[6]*wr[6] + tv[7]*wr[7];
        }
    }
    if (valid) {
        float* op = out + (size_t)g * OUT_D;
        #pragma unroll
        for (int c4 = 0; c4 < 4; ++c4) {
            float4 v;
            v.x = acc[c4*4+0] + bo2[c4*4+0];
            v.y = acc[c4*4+1] + bo2[c4*4+1];
            v.z = acc[c4*4+2] + bo2[c4*4+2];
            v.w = acc[c4*4+3] + bo2[c4*4+3];
            *(float4*)(op + c4 * 4) = v;
        }
    }
}

// ---------------------------------------------------------------------------
// Workspace (floats), aliases exploit liveness:
//   h 5.12M | As 1.28M | Bs 1.28M | H0 5.12M | H1 5.12M | P 3.2M | M 0.32M
//   t1  = H0 (dead before k_node_H writes H0)
//   t1o = H1 (dead after k_node_sheaf<1> reads H1)
//   ints: deg N | off N+1 | cursor N | inc 2E     total ≈ 87.6 MB
// ---------------------------------------------------------------------------
extern "C" void kernel_launch(void* const* d_in, const int* in_sizes, int n_in,
                              void* d_out, int out_size, void* d_ws, size_t ws_size,
                              hipStream_t stream)
{
    const float* x    = (const float*)d_in[0];
    const int*   ei   = (const int*)d_in[1];
    const float* Win1 = (const float*)d_in[2];
    const float* bin1 = (const float*)d_in[3];
    const float* Win2 = (const float*)d_in[4];
    const float* bin2 = (const float*)d_in[5];
    const float* Wm1  = (const float*)d_in[6];
    const float* bm1  = (const float*)d_in[7];
    const float* Wm2  = (const float*)d_in[8];
    const float* bm2  = (const float*)d_in[9];
    const float* Wd1  = (const float*)d_in[10];
    const float* Wd2  = (const float*)d_in[11];
    const float* Wo1  = (const float*)d_in[12];
    const float* bo1  = (const float*)d_in[13];
    const float* Wo2  = (const float*)d_in[14];
    const float* bo2  = (const float*)d_in[15];
    float* out = (float*)d_out;

    float* ws = (float*)d_ws;
    float* h  = ws;                            // N*256
    float* As = h  + (size_t)NN * HID;         // N*64
    float* Bs = As + (size_t)NN * MH;          // N*64
    float* H0 = Bs + (size_t)NN * MH;          // N*256
    float* H1 = H0 + (size_t)NN * HID;         // N*256
    float* P  = H1 + (size_t)NN * HID;         // E*16
    float* M  = P  + (size_t)EE * 16;          // N*16
    int* deg    = (int*)(M + (size_t)NN * 16); // N
    int* off    = deg + NN;                    // N+1
    int* cursor = off + NN + 1;                // N
    int* inc    = cursor + NN;                 // 2E
    float* t1  = H0;                           // alias
    float* t1o = H1;                           // alias

    const int NB = (NN + 63) / 64;             // 313

    // CSR build + M zero
    hipMemsetAsync(deg, 0, NN * sizeof(int), stream);
    hipMemsetAsync(M, 0, (size_t)NN * 16 * sizeof(float), stream);
    k_deg<<<(EE + 255) / 256, 256, 0, stream>>>(ei, deg);
    k_scan<<<1, 256, 0, stream>>>(deg, off, cursor);
    k_scatter<<<(EE + 255) / 256, 256, 0, stream>>>(ei, cursor, inc);

    // node MLP (split for occupancy) + per-edge P/Q/R
    k_mlp1<<<dim3(NB, 4), 256, 0, stream>>>(x, Win1, bin1, t1);
    k_mlp2<<<dim3(NB, 4), 256, 0, stream>>>(t1, Win2, bin2, h);
    k_mlp3<<<dim3(NB, 4), 256, 0, stream>>>(h, Wm1, As, Bs);
    k_edge_msg<<<EE / 4, 256, 0, stream>>>(ei, As, Bs, bm1, Wm2, bm2, P, M);

    // diffusion
    k_node_H<<<NN / 16, 256, 0, stream>>>(h, Wd1, Wd2, H0);
    k_node_sheaf<0><<<NN / 4, 256, 0, stream>>>(ei, off, inc, P, M, H0, h, H1,
                                                Wd1 + 16, Wd2 + 4096);
    k_node_sheaf<1><<<NN / 4, 256, 0, stream>>>(ei, off, inc, P, M, H1, h, nullptr,
                                                nullptr, nullptr);

    // output MLP (split)
    k_out1<<<dim3(NB, 4), 256, 0, stream>>>(h, Wo1, bo1, t1o);
    k_out2<<<NB, 256, 0, stream>>>(t1o, Wo2, bo2, out);
}

// Round 7
// 679.808 us; speedup vs baseline: 2.9963x; 1.1188x over previous
//
#include <hip/hip_runtime.h>

constexpr int NN   = 20000;
constexpr int EE   = 200000;
constexpr int IN_D = 500;
constexpr int HID  = 256;
constexpr int OUT_D= 16;
constexpr int MH   = 64;

// ===========================================================================
// CSR incidence build. inc entry = edge*2 + is_dst.
// ===========================================================================
__global__ __launch_bounds__(256) void k_deg(const int* __restrict__ ei, int* __restrict__ deg)
{
    int e = blockIdx.x * 256 + threadIdx.x;
    if (e < EE) {
        atomicAdd(deg + ei[e], 1);
        atomicAdd(deg + ei[EE + e], 1);
    }
}

__global__ __launch_bounds__(256) void k_scan(const int* __restrict__ deg,
                                              int* __restrict__ off, int* __restrict__ cursor)
{
    __shared__ int part[256];
    __shared__ int base[256];
    const int tid = threadIdx.x;
    const int CH = (NN + 255) / 256;
    int s = 0;
    for (int i = 0; i < CH; ++i) { int n = tid * CH + i; if (n < NN) s += deg[n]; }
    part[tid] = s;
    __syncthreads();
    if (tid == 0) { int r = 0; for (int i = 0; i < 256; ++i) { base[i] = r; r += part[i]; } }
    __syncthreads();
    int r = base[tid];
    for (int i = 0; i < CH; ++i) {
        int n = tid * CH + i;
        if (n < NN) { off[n] = r; cursor[n] = r; r += deg[n]; }
    }
    if (tid == 255) off[NN] = r;
}

__global__ __launch_bounds__(256) void k_scatter(const int* __restrict__ ei,
                                                 int* __restrict__ cursor, int* __restrict__ inc)
{
    int e = blockIdx.x * 256 + threadIdx.x;
    if (e < EE) {
        int s = ei[e], d = ei[EE + e];
        int p = atomicAdd(cursor + s, 1); inc[p] = e * 2;
        p = atomicAdd(cursor + d, 1);     inc[p] = e * 2 + 1;
    }
}

// ===========================================================================
// k_mlp1: t1 = relu(x @ Win1.T + bin1).  grid (N/64, 4); block = 16 c's.
// ===========================================================================
__global__ __launch_bounds__(256, 4) void k_mlp1(
    const float* __restrict__ x, const float* __restrict__ Win1, const float* __restrict__ bin1,
    float* __restrict__ t1)
{
    __shared__ float xs[64 * 101];
    const int tid  = threadIdx.x;
    const int w    = __builtin_amdgcn_readfirstlane(tid >> 6);
    const int lane = tid & 63;
    const int node0 = blockIdx.x * 64;
    const int cbase = blockIdx.y * 16 + w * 4;
    const int g = min(node0 + lane, NN - 1);
    const bool valid = (node0 + lane) < NN;

    float acc[4] = {0.f, 0.f, 0.f, 0.f};

    for (int j = 0; j < 5; ++j) {
        __syncthreads();
        for (int i = tid; i < 1600; i += 256) {
            int n = i / 25, k4 = i % 25;
            int gr = min(node0 + n, NN - 1);
            float4 v = ((const float4*)x)[(size_t)gr * 125 + j * 25 + k4];
            float* d = &xs[n * 101 + k4 * 4];
            d[0] = v.x; d[1] = v.y; d[2] = v.z; d[3] = v.w;
        }
        __syncthreads();
        for (int kt = 0; kt < 25; ++kt) {
            float x0 = xs[lane * 101 + kt * 4 + 0];
            float x1 = xs[lane * 101 + kt * 4 + 1];
            float x2 = xs[lane * 101 + kt * 4 + 2];
            float x3 = xs[lane * 101 + kt * 4 + 3];
            #pragma unroll
            for (int cc = 0; cc < 4; ++cc) {
                const float* wr = Win1 + (size_t)(cbase + cc) * IN_D + j * 100 + kt * 4;
                acc[cc] += x0 * wr[0] + x1 * wr[1] + x2 * wr[2] + x3 * wr[3];
            }
        }
    }
    if (valid) {
        float4 v;
        v.x = fmaxf(acc[0] + bin1[cbase + 0], 0.f);
        v.y = fmaxf(acc[1] + bin1[cbase + 1], 0.f);
        v.z = fmaxf(acc[2] + bin1[cbase + 2], 0.f);
        v.w = fmaxf(acc[3] + bin1[cbase + 3], 0.f);
        *(float4*)(t1 + (size_t)g * MH + cbase) = v;
    }
}

// ===========================================================================
// k_mlp2: h = t1 @ Win2.T + bin2.  grid (N/64, 4).
// ===========================================================================
__global__ __launch_bounds__(256, 4) void k_mlp2(
    const float* __restrict__ t1, const float* __restrict__ Win2, const float* __restrict__ bin2,
    float* __restrict__ h)
{
    __shared__ float ts[64 * 65];
    const int tid  = threadIdx.x;
    const int w    = __builtin_amdgcn_readfirstlane(tid >> 6);
    const int lane = tid & 63;
    const int node0 = blockIdx.x * 64;
    const int cbase = blockIdx.y * 64 + w * 16;
    const int g = min(node0 + lane, NN - 1);
    const bool valid = (node0 + lane) < NN;

    for (int i = tid; i < 1024; i += 256) {
        int n = i >> 4, k4 = i & 15;
        int gr = min(node0 + n, NN - 1);
        float4 v = ((const float4*)t1)[(size_t)gr * 16 + k4];
        float* d = &ts[n * 65 + k4 * 4];
        d[0] = v.x; d[1] = v.y; d[2] = v.z; d[3] = v.w;
    }
    __syncthreads();

    float acc[16];
    #pragma unroll
    for (int i = 0; i < 16; ++i) acc[i] = 0.f;
    for (int kt = 0; kt < 8; ++kt) {
        float tv[8];
        #pragma unroll
        for (int i = 0; i < 8; ++i) tv[i] = ts[lane * 65 + kt * 8 + i];
        #pragma unroll
        for (int cc = 0; cc < 16; ++cc) {
            const float* wr = Win2 + (size_t)(cbase + cc) * MH + kt * 8;
            acc[cc] += tv[0]*wr[0] + tv[1]*wr[1] + tv[2]*wr[2] + tv[3]*wr[3]
                     + tv[4]*wr[4] + tv[5]*wr[5] + tv[6]*wr[6] + tv[7]*wr[7];
        }
    }
    if (valid) {
        float* hp = h + (size_t)g * HID + cbase;
        #pragma unroll
        for (int c4 = 0; c4 < 4; ++c4) {
            float4 v;
            v.x = acc[c4*4+0] + bin2[cbase + c4*4+0];
            v.y = acc[c4*4+1] + bin2[cbase + c4*4+1];
            v.z = acc[c4*4+2] + bin2[cbase + c4*4+2];
            v.w = acc[c4*4+3] + bin2[cbase + c4*4+3];
            *(float4*)(hp + c4 * 4) = v;
        }
    }
}

// ===========================================================================
// k_mlp3: As = h @ Wa.T, Bs = h @ Wb.T.  grid (N/64, 4).
// ===========================================================================
__global__ __launch_bounds__(256, 4) void k_mlp3(
    const float* __restrict__ h, const float* __restrict__ Wm1,
    float* __restrict__ As, float* __restrict__ Bs)
{
    __shared__ float hsm[64 * 65];
    const int tid  = threadIdx.x;
    const int w    = __builtin_amdgcn_readfirstlane(tid >> 6);
    const int lane = tid & 63;
    const int node0 = blockIdx.x * 64;
    const int vcb = blockIdx.y * 32 + w * 8;
    const int which = vcb >> 6;
    const int cb = vcb & 63;
    const int g = min(node0 + lane, NN - 1);
    const bool valid = (node0 + lane) < NN;

    float acc[8];
    #pragma unroll
    for (int i = 0; i < 8; ++i) acc[i] = 0.f;

    for (int ch = 0; ch < 4; ++ch) {
        __syncthreads();
        for (int i = tid; i < 1024; i += 256) {
            int n = i >> 4, k4 = i & 15;
            int gr = min(node0 + n, NN - 1);
            float4 v = ((const float4*)h)[(size_t)gr * 64 + ch * 16 + k4];
            float* d = &hsm[n * 65 + k4 * 4];
            d[0] = v.x; d[1] = v.y; d[2] = v.z; d[3] = v.w;
        }
        __syncthreads();
        for (int kt = 0; kt < 8; ++kt) {
            float tv[8];
            #pragma unroll
            for (int i = 0; i < 8; ++i) tv[i] = hsm[lane * 65 + kt * 8 + i];
            #pragma unroll
            for (int jj = 0; jj < 8; ++jj) {
                const float* wr = Wm1 + (size_t)(cb + jj) * (2 * HID) + which * HID
                                + ch * 64 + kt * 8;
                acc[jj] += tv[0]*wr[0] + tv[1]*wr[1] + tv[2]*wr[2] + tv[3]*wr[3]
                         + tv[4]*wr[4] + tv[5]*wr[5] + tv[6]*wr[6] + tv[7]*wr[7];
            }
        }
    }
    if (valid) {
        float* dst = (which ? Bs : As) + (size_t)g * MH + cb;
        float4 v0, v1;
        v0.x = acc[0]; v0.y = acc[1]; v0.z = acc[2]; v0.w = acc[3];
        v1.x = acc[4]; v1.y = acc[5]; v1.z = acc[6]; v1.w = acc[7];
        *(float4*)(dst + 0) = v0;
        *(float4*)(dst + 4) = v1;
    }
}

// ===========================================================================
// k_edge_msg — 64 edges/block, register-tiled GEMV.
//   phase 1: wave w gathers edges w*16..w*16+15 -> plds (rows padded 68)
//   phase 2: 2048 outputs = 128 pairs x 16 j; thread tile 4 pairs x 2 j
//   phase 3: thread = (edge, row j): P float4 write + 8 atomics into M
// LDS: plds 34.8KB + wm2s 4.4KB + fls 8.7KB = 47.9KB -> 3 blocks/CU
// ===========================================================================
__global__ __launch_bounds__(256, 3) void k_edge_msg(
    const int* __restrict__ ei, const float* __restrict__ As, const float* __restrict__ Bs,
    const float* __restrict__ bm1, const float* __restrict__ Wm2, const float* __restrict__ bm2,
    float* __restrict__ P, float* __restrict__ M)
{
    __shared__ float plds[128 * 68];  // row = e_local*2+which
    __shared__ float wm2s[16 * 68];
    __shared__ float fls[128 * 17];
    const int tid = threadIdx.x;
    const int w = tid >> 6, t = tid & 63;
    const int e0 = blockIdx.x * 64;

    // stage Wm2 (16x64)
    for (int i = tid; i < 1024; i += 256)
        wm2s[(i >> 6) * 68 + (i & 63)] = Wm2[i];

    const float bm = bm1[t];

    // phase 1: 16 edges per wave, 4 coalesced 256B gathers each
    for (int r = 0; r < 16; ++r) {
        const int el = w * 16 + r;
        const int e = e0 + el;
        const int src = ei[e], dst = ei[EE + e];
        float a_s = As[(size_t)src * MH + t];
        float b_d = Bs[(size_t)dst * MH + t];
        float a_d = As[(size_t)dst * MH + t];
        float b_s = Bs[(size_t)src * MH + t];
        plds[(el * 2 + 0) * 68 + t] = fmaxf(a_s + b_d + bm, 0.f);
        plds[(el * 2 + 1) * 68 + t] = fmaxf(a_d + b_s + bm, 0.f);
    }
    __syncthreads();

    // phase 2: register-tiled GEMV: pairs 4*pg..+3, j = 2*jg, 2*jg+1
    {
        const int pg = tid & 31;        // 32 pair-groups
        const int jg = tid >> 5;        // 8 j-groups
        const int j0 = jg * 2;
        float acc[4][2];
        #pragma unroll
        for (int i = 0; i < 4; ++i) { acc[i][0] = 0.f; acc[i][1] = 0.f; }

        const float4* w0 = (const float4*)&wm2s[(j0 + 0) * 68];
        const float4* w1 = (const float4*)&wm2s[(j0 + 1) * 68];
        const float4* p0 = (const float4*)&plds[(4 * pg + 0) * 68];
        const float4* p1 = (const float4*)&plds[(4 * pg + 1) * 68];
        const float4* p2 = (const float4*)&plds[(4 * pg + 2) * 68];
        const float4* p3 = (const float4*)&plds[(4 * pg + 3) * 68];

        #pragma unroll
        for (int k4 = 0; k4 < 16; ++k4) {
            float4 wv0 = w0[k4], wv1 = w1[k4];
            float4 a = p0[k4], b = p1[k4], c = p2[k4], d = p3[k4];
            acc[0][0] += a.x*wv0.x + a.y*wv0.y + a.z*wv0.z + a.w*wv0.w;
            acc[0][1] += a.x*wv1.x + a.y*wv1.y + a.z*wv1.z + a.w*wv1.w;
            acc[1][0] += b.x*wv0.x + b.y*wv0.y + b.z*wv0.z + b.w*wv0.w;
            acc[1][1] += b.x*wv1.x + b.y*wv1.y + b.z*wv1.z + b.w*wv1.w;
            acc[2][0] += c.x*wv0.x + c.y*wv0.y + c.z*wv0.z + c.w*wv0.w;
            acc[2][1] += c.x*wv1.x + c.y*wv1.y + c.z*wv1.z + c.w*wv1.w;
            acc[3][0] += d.x*wv0.x + d.y*wv0.y + d.z*wv0.z + d.w*wv0.w;
            acc[3][1] += d.x*wv1.x + d.y*wv1.y + d.z*wv1.z + d.w*wv1.w;
        }
        float bm2a = bm2[j0], bm2b = bm2[j0 + 1];
        #pragma unroll
        for (int i = 0; i < 4; ++i) {
            fls[(4 * pg + i) * 17 + j0]     = acc[i][0] + bm2a;
            fls[(4 * pg + i) * 17 + j0 + 1] = acc[i][1] + bm2b;
        }
    }
    __syncthreads();

    // phase 3: thread = (edge el, row cg); P row write + M atomics
    {
        const int el = tid >> 2, cg = tid & 3;
        const float* f0 = &fls[(el * 2 + 0) * 17];
        const float* f1 = &fls[(el * 2 + 1) * 17];
        float a0 = f0[0*4+cg], a1 = f0[1*4+cg], a2 = f0[2*4+cg], a3 = f0[3*4+cg];
        float b0 = f1[0*4+cg], b1 = f1[1*4+cg], b2 = f1[2*4+cg], b3 = f1[3*4+cg];
        float4 pp, qq, rr;
        {
            float c0, c1, c2, c3;
            c0 = f1[0]; c1 = f1[4]; c2 = f1[8]; c3 = f1[12];
            pp.x = a0*c0 + a1*c1 + a2*c2 + a3*c3;
            rr.x = b0*c0 + b1*c1 + b2*c2 + b3*c3;
            c0 = f1[1]; c1 = f1[5]; c2 = f1[9]; c3 = f1[13];
            pp.y = a0*c0 + a1*c1 + a2*c2 + a3*c3;
            rr.y = b0*c0 + b1*c1 + b2*c2 + b3*c3;
            c0 = f1[2]; c1 = f1[6]; c2 = f1[10]; c3 = f1[14];
            pp.z = a0*c0 + a1*c1 + a2*c2 + a3*c3;
            rr.z = b0*c0 + b1*c1 + b2*c2 + b3*c3;
            c0 = f1[3]; c1 = f1[7]; c2 = f1[11]; c3 = f1[15];
            pp.w = a0*c0 + a1*c1 + a2*c2 + a3*c3;
            rr.w = b0*c0 + b1*c1 + b2*c2 + b3*c3;
            c0 = f0[0]; c1 = f0[4]; c2 = f0[8]; c3 = f0[12];
            qq.x = a0*c0 + a1*c1 + a2*c2 + a3*c3;
            c0 = f0[1]; c1 = f0[5]; c2 = f0[9]; c3 = f0[13];
            qq.y = a0*c0 + a1*c1 + a2*c2 + a3*c3;
            c0 = f0[2]; c1 = f0[6]; c2 = f0[10]; c3 = f0[14];
            qq.z = a0*c0 + a1*c1 + a2*c2 + a3*c3;
            c0 = f0[3]; c1 = f0[7]; c2 = f0[11]; c3 = f0[15];
            qq.w = a0*c0 + a1*c1 + a2*c2 + a3*c3;
        }
        const int eg = e0 + el;
        *(float4*)(P + (size_t)eg * 16 + cg * 4) = pp;
        const int s2 = ei[eg], d2 = ei[EE + eg];
        float* ms = M + (size_t)s2 * 16 + cg * 4;
        float* md = M + (size_t)d2 * 16 + cg * 4;
        atomicAdd(ms + 0, qq.x); atomicAdd(ms + 1, qq.y);
        atomicAdd(ms + 2, qq.z); atomicAdd(ms + 3, qq.w);
        atomicAdd(md + 0, rr.x); atomicAdd(md + 1, rr.y);
        atomicAdd(md + 2, rr.z); atomicAdd(md + 3, rr.w);
    }
}

// ===========================================================================
// k_node_H — H0 = (Wd1.T @ xb) @ Wd2.T per node.
// ===========================================================================
__global__ __launch_bounds__(256) void k_node_H(
    const float* __restrict__ xb,
    const float* __restrict__ Wd1l, const float* __restrict__ Wd2l,
    float* __restrict__ H)
{
    __shared__ float wt[64][68];
    __shared__ float tl[4][4][64];
    const int tid = threadIdx.x;
    const int w = tid >> 6, t = tid & 63;

    for (int i = tid; i < 4096; i += 256) wt[i >> 6][i & 63] = Wd2l[i];
    float wd1[16];
    #pragma unroll
    for (int i = 0; i < 16; ++i) wd1[i] = Wd1l[i];
    __syncthreads();

    for (int rep = 0; rep < 4; ++rep) {
        const int n = blockIdx.x * 16 + w * 4 + rep;
        float xv[4];
        #pragma unroll
        for (int j = 0; j < 4; ++j) xv[j] = xb[(size_t)n * HID + j * 64 + t];
        #pragma unroll
        for (int i = 0; i < 4; ++i)
            tl[w][i][t] = wd1[0 + i] * xv[0] + wd1[4 + i] * xv[1] +
                          wd1[8 + i] * xv[2] + wd1[12 + i] * xv[3];
        __syncthreads();
        float a0 = 0, a1 = 0, a2 = 0, a3 = 0;
        #pragma unroll
        for (int f = 0; f < 64; f += 4) {
            float4 wv = *(const float4*)&wt[t][f];
            float4 t0 = *(const float4*)&tl[w][0][f];
            float4 t1 = *(const float4*)&tl[w][1][f];
            float4 t2 = *(const float4*)&tl[w][2][f];
            float4 t3 = *(const float4*)&tl[w][3][f];
            a0 += t0.x * wv.x + t0.y * wv.y + t0.z * wv.z + t0.w * wv.w;
            a1 += t1.x * wv.x + t1.y * wv.y + t1.z * wv.z + t1.w * wv.w;
            a2 += t2.x * wv.x + t2.y * wv.y + t2.z * wv.z + t2.w * wv.w;
            a3 += t3.x * wv.x + t3.y * wv.y + t3.z * wv.z + t3.w * wv.w;
        }
        __syncthreads();
        size_t base = (size_t)n * HID + t;
        H[base + 0 * 64] = a0;
        H[base + 1 * 64] = a1;
        H[base + 2 * 64] = a2;
        H[base + 3 * 64] = a3;
    }
}

// ===========================================================================
// k_node_sheaf<LAYER> — CSR gather, no atomics; xb update in place;
// LAYER==0 also produces next-layer H.
// ===========================================================================
template<int LAYER>
__global__ __launch_bounds__(256) void k_node_sheaf(
    const int* __restrict__ ei, const int* __restrict__ off, const int* __restrict__ inc,
    const float* __restrict__ P, const float* __restrict__ M,
    const float* __restrict__ Hin, float* __restrict__ h, float* __restrict__ Hout,
    const float* __restrict__ Wd1l, const float* __restrict__ Wd2l)
{
    __shared__ float wt[64][68];
    __shared__ float tl[4][4][64];
    const int tid = threadIdx.x;
    const int w = tid >> 6, t = tid & 63;

    if (LAYER == 0) {
        for (int i = tid; i < 4096; i += 256) wt[i >> 6][i & 63] = Wd2l[i];
    }
    float wd1[16];
    if (LAYER == 0) {
        #pragma unroll
        for (int i = 0; i < 16; ++i) wd1[i] = Wd1l[i];
        __syncthreads();
    }

    const int n = blockIdx.x * 4 + w;
    float Hn[4];
    #pragma unroll
    for (int k = 0; k < 4; ++k) Hn[k] = Hin[(size_t)n * HID + k * 64 + t];

    float Mn[16];
    #pragma unroll
    for (int c = 0; c < 16; ++c) Mn[c] = M[(size_t)n * 16 + c];

    float acc[4];
    #pragma unroll
    for (int j = 0; j < 4; ++j)
        acc[j] = Mn[j*4+0]*Hn[0] + Mn[j*4+1]*Hn[1] + Mn[j*4+2]*Hn[2] + Mn[j*4+3]*Hn[3];

    const int p0 = off[n], p1 = off[n + 1];
    for (int p = p0; p < p1; ++p) {
        int v = inc[p];
        int e = v >> 1, isdst = v & 1;
        int other = isdst ? ei[e] : ei[EE + e];
        float Ho[4];
        #pragma unroll
        for (int k = 0; k < 4; ++k) Ho[k] = Hin[(size_t)other * HID + k * 64 + t];
        const float* Pe = P + (size_t)e * 16;
        if (!isdst) {
            #pragma unroll
            for (int j = 0; j < 4; ++j)
                acc[j] -= Pe[j*4+0]*Ho[0] + Pe[j*4+1]*Ho[1] + Pe[j*4+2]*Ho[2] + Pe[j*4+3]*Ho[3];
        } else {
            #pragma unroll
            for (int j = 0; j < 4; ++j)
                acc[j] -= Pe[0*4+j]*Ho[0] + Pe[1*4+j]*Ho[1] + Pe[2*4+j]*Ho[2] + Pe[3*4+j]*Ho[3];
        }
    }

    float xv[4];
    #pragma unroll
    for (int j = 0; j < 4; ++j) {
        size_t idx = (size_t)n * HID + j * 64 + t;
        float vv = h[idx] - fmaxf(acc[j], 0.f);
        h[idx] = vv;
        xv[j] = vv;
    }

    if (LAYER == 0) {
        #pragma unroll
        for (int i = 0; i < 4; ++i)
            tl[w][i][t] = wd1[0 + i] * xv[0] + wd1[4 + i] * xv[1] +
                          wd1[8 + i] * xv[2] + wd1[12 + i] * xv[3];
        __syncthreads();
        float a0 = 0, a1 = 0, a2 = 0, a3 = 0;
        #pragma unroll
        for (int f = 0; f < 64; f += 4) {
            float4 wv = *(const float4*)&wt[t][f];
            float4 t0 = *(const float4*)&tl[w][0][f];
            float4 t1 = *(const float4*)&tl[w][1][f];
            float4 t2 = *(const float4*)&tl[w][2][f];
            float4 t3 = *(const float4*)&tl[w][3][f];
            a0 += t0.x * wv.x + t0.y * wv.y + t0.z * wv.z + t0.w * wv.w;
            a1 += t1.x * wv.x + t1.y * wv.y + t1.z * wv.z + t1.w * wv.w;
            a2 += t2.x * wv.x + t2.y * wv.y + t2.z * wv.z + t2.w * wv.w;
            a3 += t3.x * wv.x + t3.y * wv.y + t3.z * wv.z + t3.w * wv.w;
        }
        size_t base = (size_t)n * HID + t;
        Hout[base + 0 * 64] = a0;
        Hout[base + 1 * 64] = a1;
        Hout[base + 2 * 64] = a2;
        Hout[base + 3 * 64] = a3;
    }
}

// ===========================================================================
// k_out1: t1o = relu(xb @ Wo1.T + bo1).  grid (N/64, 4).
// ===========================================================================
__global__ __launch_bounds__(256, 4) void k_out1(
    const float* __restrict__ xb, const float* __restrict__ Wo1, const float* __restrict__ bo1,
    float* __restrict__ t1o)
{
    __shared__ float xr[64 * 129];
    const int tid  = threadIdx.x;
    const int w    = __builtin_amdgcn_readfirstlane(tid >> 6);
    const int lane = tid & 63;
    const int node0 = blockIdx.x * 64;
    const int cbase = blockIdx.y * 16 + w * 4;
    const int g = min(node0 + lane, NN - 1);
    const bool valid = (node0 + lane) < NN;

    float acc[4] = {0.f, 0.f, 0.f, 0.f};

    for (int j = 0; j < 2; ++j) {
        __syncthreads();
        for (int i = tid; i < 2048; i += 256) {
            int n = i >> 5, k4 = i & 31;
            int gr = min(node0 + n, NN - 1);
            float4 v = ((const float4*)xb)[(size_t)gr * 64 + j * 32 + k4];
            float* d = &xr[n * 129 + k4 * 4];
            d[0] = v.x; d[1] = v.y; d[2] = v.z; d[3] = v.w;
        }
        __syncthreads();
        for (int kt = 0; kt < 32; ++kt) {
            float x0 = xr[lane * 129 + kt * 4 + 0];
            float x1 = xr[lane * 129 + kt * 4 + 1];
            float x2 = xr[lane * 129 + kt * 4 + 2];
            float x3 = xr[lane * 129 + kt * 4 + 3];
            #pragma unroll
            for (int cc = 0; cc < 4; ++cc) {
                const float* wr = Wo1 + (size_t)(cbase + cc) * HID + j * 128 + kt * 4;
                acc[cc] += x0 * wr[0] + x1 * wr[1] + x2 * wr[2] + x3 * wr[3];
            }
        }
    }
    if (valid) {
        float4 v;
        v.x = fmaxf(acc[0] + bo1[cbase + 0], 0.f);
        v.y = fmaxf(acc[1] + bo1[cbase + 1], 0.f);
        v.z = fmaxf(acc[2] + bo1[cbase + 2], 0.f);
        v.w = fmaxf(acc[3] + bo1[cbase + 3], 0.f);
        *(float4*)(t1o + (size_t)g * MH + cbase) = v;
    }
}

// ===========================================================================
// k_out2: out = t1o @ Wo2.T + bo2.
// ===========================================================================
__global__ __launch_bounds__(256, 4) void k_out2(
    const float* __restrict__ t1o, const float* __restrict__ Wo2, const float* __restrict__ bo2,
    float* __restrict__ out)
{
    __shared__ float ts[64 * 65];
    const int tid  = threadIdx.x;
    const int lane = tid & 63;
    const int node0 = blockIdx.x * 64;
    const int g = min(node0 + lane, NN - 1);
    const bool valid = (node0 + lane) < NN;

    for (int i = tid; i < 1024; i += 256) {
        int n = i >> 4, k4 = i & 15;
        int gr = min(node0 + n, NN - 1);
        float4 v = ((const float4*)t1o)[(size_t)gr * 16 + k4];
        float* d = &ts[n * 65 + k4 * 4];
        d[0] = v.x; d[1] = v.y; d[2] = v.z; d[3] = v.w;
    }
    __syncthreads();

    float acc[16];
    #pragma unroll
    for (int i = 0; i < 16; ++i) acc[i] = 0.f;
    for (int kt = 0; kt < 8; ++kt) {
        float tv[8];
        #pragma unroll
        for (int i = 0; i < 8; ++i) tv[i] = ts[lane * 65 + kt * 8 + i];
        #pragma unroll
        for (int jj = 0; jj < 16; ++jj) {
            const float* wr = Wo2 + (size_t)jj * MH + kt * 8;
            acc[jj] += tv[0]*wr[0] + tv[1]*wr[1] + tv[2]*wr[2] + tv[3]*wr[3]
                     + tv[4]*wr[4] + tv[5]*wr[5] + tv[6]*wr[6] + tv[7]*wr[7];
        }
    }
    if (valid) {
        float* op = out + (size_t)g * OUT_D;
        #pragma unroll
        for (int c4 = 0; c4 < 4; ++c4) {
            float4 v;
            v.x = acc[c4*4+0] + bo2[c4*4+0];
            v.y = acc[c4*4+1] + bo2[c4*4+1];
            v.z = acc[c4*4+2] + bo2[c4*4+2];
            v.w = acc[c4*4+3] + bo2[c4*4+3];
            *(float4*)(op + c4 * 4) = v;
        }
    }
}

// ---------------------------------------------------------------------------
// Workspace layout (same as round 5; ≈87.6 MB): t1=H0, t1o=H1 aliases.
// ---------------------------------------------------------------------------
extern "C" void kernel_launch(void* const* d_in, const int* in_sizes, int n_in,
                              void* d_out, int out_size, void* d_ws, size_t ws_size,
                              hipStream_t stream)
{
    const float* x    = (const float*)d_in[0];
    const int*   ei   = (const int*)d_in[1];
    const float* Win1 = (const float*)d_in[2];
    const float* bin1 = (const float*)d_in[3];
    const float* Win2 = (const float*)d_in[4];
    const float* bin2 = (const float*)d_in[5];
    const float* Wm1  = (const float*)d_in[6];
    const float* bm1  = (const float*)d_in[7];
    const float* Wm2  = (const float*)d_in[8];
    const float* bm2  = (const float*)d_in[9];
    const float* Wd1  = (const float*)d_in[10];
    const float* Wd2  = (const float*)d_in[11];
    const float* Wo1  = (const float*)d_in[12];
    const float* bo1  = (const float*)d_in[13];
    const float* Wo2  = (const float*)d_in[14];
    const float* bo2  = (const float*)d_in[15];
    float* out = (float*)d_out;

    float* ws = (float*)d_ws;
    float* h  = ws;                            // N*256
    float* As = h  + (size_t)NN * HID;         // N*64
    float* Bs = As + (size_t)NN * MH;          // N*64
    float* H0 = Bs + (size_t)NN * MH;          // N*256
    float* H1 = H0 + (size_t)NN * HID;         // N*256
    float* P  = H1 + (size_t)NN * HID;         // E*16
    float* M  = P  + (size_t)EE * 16;          // N*16
    int* deg    = (int*)(M + (size_t)NN * 16); // N
    int* off    = deg + NN;                    // N+1
    int* cursor = off + NN + 1;                // N
    int* inc    = cursor + NN;                 // 2E
    float* t1  = H0;                           // alias
    float* t1o = H1;                           // alias

    const int NB = (NN + 63) / 64;             // 313

    // CSR build + M zero
    hipMemsetAsync(deg, 0, NN * sizeof(int), stream);
    hipMemsetAsync(M, 0, (size_t)NN * 16 * sizeof(float), stream);
    k_deg<<<(EE + 255) / 256, 256, 0, stream>>>(ei, deg);
    k_scan<<<1, 256, 0, stream>>>(deg, off, cursor);
    k_scatter<<<(EE + 255) / 256, 256, 0, stream>>>(ei, cursor, inc);

    // node MLP + per-edge P/Q/R
    k_mlp1<<<dim3(NB, 4), 256, 0, stream>>>(x, Win1, bin1, t1);
    k_mlp2<<<dim3(NB, 4), 256, 0, stream>>>(t1, Win2, bin2, h);
    k_mlp3<<<dim3(NB, 4), 256, 0, stream>>>(h, Wm1, As, Bs);
    k_edge_msg<<<EE / 64, 256, 0, stream>>>(ei, As, Bs, bm1, Wm2, bm2, P, M);

    // diffusion
    k_node_H<<<NN / 16, 256, 0, stream>>>(h, Wd1, Wd2, H0);
    k_node_sheaf<0><<<NN / 4, 256, 0, stream>>>(ei, off, inc, P, M, H0, h, H1,
                                                Wd1 + 16, Wd2 + 4096);
    k_node_sheaf<1><<<NN / 4, 256, 0, stream>>>(ei, off, inc, P, M, H1, h, nullptr,
                                                nullptr, nullptr);

    // output MLP
    k_out1<<<dim3(NB, 4), 256, 0, stream>>>(h, Wo1, bo1, t1o);
    k_out2<<<NB, 256, 0, stream>>>(t1o, Wo2, bo2, out);
}

// Round 8
// 647.202 us; speedup vs baseline: 3.1473x; 1.0504x over previous
//
#include <hip/hip_runtime.h>

constexpr int NN   = 20000;
constexpr int EE   = 200000;
constexpr int IN_D = 500;
constexpr int HID  = 256;
constexpr int OUT_D= 16;
constexpr int MH   = 64;

// ===========================================================================
// CSR incidence build. inc entry = edge*2 + is_dst; inc2 entry = other node.
// ===========================================================================
__global__ __launch_bounds__(256) void k_deg(const int* __restrict__ ei, int* __restrict__ deg)
{
    int e = blockIdx.x * 256 + threadIdx.x;
    if (e < EE) {
        atomicAdd(deg + ei[e], 1);
        atomicAdd(deg + ei[EE + e], 1);
    }
}

__global__ __launch_bounds__(256) void k_scan(const int* __restrict__ deg,
                                              int* __restrict__ off, int* __restrict__ cursor)
{
    __shared__ int part[256];
    __shared__ int base[256];
    const int tid = threadIdx.x;
    const int CH = (NN + 255) / 256;
    int s = 0;
    for (int i = 0; i < CH; ++i) { int n = tid * CH + i; if (n < NN) s += deg[n]; }
    part[tid] = s;
    __syncthreads();
    if (tid == 0) { int r = 0; for (int i = 0; i < 256; ++i) { base[i] = r; r += part[i]; } }
    __syncthreads();
    int r = base[tid];
    for (int i = 0; i < CH; ++i) {
        int n = tid * CH + i;
        if (n < NN) { off[n] = r; cursor[n] = r; r += deg[n]; }
    }
    if (tid == 255) off[NN] = r;
}

__global__ __launch_bounds__(256) void k_scatter(const int* __restrict__ ei,
                                                 int* __restrict__ cursor,
                                                 int* __restrict__ inc, int* __restrict__ inc2)
{
    int e = blockIdx.x * 256 + threadIdx.x;
    if (e < EE) {
        int s = ei[e], d = ei[EE + e];
        int p = atomicAdd(cursor + s, 1); inc[p] = e * 2;     inc2[p] = d;
        p = atomicAdd(cursor + d, 1);     inc[p] = e * 2 + 1; inc2[p] = s;
    }
}

// ===========================================================================
// k_mlp1: t1 = relu(x @ Win1.T + bin1).  grid (N/64, 4).
// ===========================================================================
__global__ __launch_bounds__(256, 4) void k_mlp1(
    const float* __restrict__ x, const float* __restrict__ Win1, const float* __restrict__ bin1,
    float* __restrict__ t1)
{
    __shared__ float xs[64 * 101];
    const int tid  = threadIdx.x;
    const int w    = __builtin_amdgcn_readfirstlane(tid >> 6);
    const int lane = tid & 63;
    const int node0 = blockIdx.x * 64;
    const int cbase = blockIdx.y * 16 + w * 4;
    const int g = min(node0 + lane, NN - 1);
    const bool valid = (node0 + lane) < NN;

    float acc[4] = {0.f, 0.f, 0.f, 0.f};

    for (int j = 0; j < 5; ++j) {
        __syncthreads();
        for (int i = tid; i < 1600; i += 256) {
            int n = i / 25, k4 = i % 25;
            int gr = min(node0 + n, NN - 1);
            float4 v = ((const float4*)x)[(size_t)gr * 125 + j * 25 + k4];
            float* d = &xs[n * 101 + k4 * 4];
            d[0] = v.x; d[1] = v.y; d[2] = v.z; d[3] = v.w;
        }
        __syncthreads();
        for (int kt = 0; kt < 25; ++kt) {
            float x0 = xs[lane * 101 + kt * 4 + 0];
            float x1 = xs[lane * 101 + kt * 4 + 1];
            float x2 = xs[lane * 101 + kt * 4 + 2];
            float x3 = xs[lane * 101 + kt * 4 + 3];
            #pragma unroll
            for (int cc = 0; cc < 4; ++cc) {
                const float* wr = Win1 + (size_t)(cbase + cc) * IN_D + j * 100 + kt * 4;
                acc[cc] += x0 * wr[0] + x1 * wr[1] + x2 * wr[2] + x3 * wr[3];
            }
        }
    }
    if (valid) {
        float4 v;
        v.x = fmaxf(acc[0] + bin1[cbase + 0], 0.f);
        v.y = fmaxf(acc[1] + bin1[cbase + 1], 0.f);
        v.z = fmaxf(acc[2] + bin1[cbase + 2], 0.f);
        v.w = fmaxf(acc[3] + bin1[cbase + 3], 0.f);
        *(float4*)(t1 + (size_t)g * MH + cbase) = v;
    }
}

// ===========================================================================
// k_mlp2: h = t1 @ Win2.T + bin2.  grid (N/64, 4).
// ===========================================================================
__global__ __launch_bounds__(256, 4) void k_mlp2(
    const float* __restrict__ t1, const float* __restrict__ Win2, const float* __restrict__ bin2,
    float* __restrict__ h)
{
    __shared__ float ts[64 * 65];
    const int tid  = threadIdx.x;
    const int w    = __builtin_amdgcn_readfirstlane(tid >> 6);
    const int lane = tid & 63;
    const int node0 = blockIdx.x * 64;
    const int cbase = blockIdx.y * 64 + w * 16;
    const int g = min(node0 + lane, NN - 1);
    const bool valid = (node0 + lane) < NN;

    for (int i = tid; i < 1024; i += 256) {
        int n = i >> 4, k4 = i & 15;
        int gr = min(node0 + n, NN - 1);
        float4 v = ((const float4*)t1)[(size_t)gr * 16 + k4];
        float* d = &ts[n * 65 + k4 * 4];
        d[0] = v.x; d[1] = v.y; d[2] = v.z; d[3] = v.w;
    }
    __syncthreads();

    float acc[16];
    #pragma unroll
    for (int i = 0; i < 16; ++i) acc[i] = 0.f;
    for (int kt = 0; kt < 8; ++kt) {
        float tv[8];
        #pragma unroll
        for (int i = 0; i < 8; ++i) tv[i] = ts[lane * 65 + kt * 8 + i];
        #pragma unroll
        for (int cc = 0; cc < 16; ++cc) {
            const float* wr = Win2 + (size_t)(cbase + cc) * MH + kt * 8;
            acc[cc] += tv[0]*wr[0] + tv[1]*wr[1] + tv[2]*wr[2] + tv[3]*wr[3]
                     + tv[4]*wr[4] + tv[5]*wr[5] + tv[6]*wr[6] + tv[7]*wr[7];
        }
    }
    if (valid) {
        float* hp = h + (size_t)g * HID + cbase;
        #pragma unroll
        for (int c4 = 0; c4 < 4; ++c4) {
            float4 v;
            v.x = acc[c4*4+0] + bin2[cbase + c4*4+0];
            v.y = acc[c4*4+1] + bin2[cbase + c4*4+1];
            v.z = acc[c4*4+2] + bin2[cbase + c4*4+2];
            v.w = acc[c4*4+3] + bin2[cbase + c4*4+3];
            *(float4*)(hp + c4 * 4) = v;
        }
    }
}

// ===========================================================================
// k_mlp3: As = h @ Wa.T, Bs = h @ Wb.T.  grid (N/64, 4).
// ===========================================================================
__global__ __launch_bounds__(256, 4) void k_mlp3(
    const float* __restrict__ h, const float* __restrict__ Wm1,
    float* __restrict__ As, float* __restrict__ Bs)
{
    __shared__ float hsm[64 * 65];
    const int tid  = threadIdx.x;
    const int w    = __builtin_amdgcn_readfirstlane(tid >> 6);
    const int lane = tid & 63;
    const int node0 = blockIdx.x * 64;
    const int vcb = blockIdx.y * 32 + w * 8;
    const int which = vcb >> 6;
    const int cb = vcb & 63;
    const int g = min(node0 + lane, NN - 1);
    const bool valid = (node0 + lane) < NN;

    float acc[8];
    #pragma unroll
    for (int i = 0; i < 8; ++i) acc[i] = 0.f;

    for (int ch = 0; ch < 4; ++ch) {
        __syncthreads();
        for (int i = tid; i < 1024; i += 256) {
            int n = i >> 4, k4 = i & 15;
            int gr = min(node0 + n, NN - 1);
            float4 v = ((const float4*)h)[(size_t)gr * 64 + ch * 16 + k4];
            float* d = &hsm[n * 65 + k4 * 4];
            d[0] = v.x; d[1] = v.y; d[2] = v.z; d[3] = v.w;
        }
        __syncthreads();
        for (int kt = 0; kt < 8; ++kt) {
            float tv[8];
            #pragma unroll
            for (int i = 0; i < 8; ++i) tv[i] = hsm[lane * 65 + kt * 8 + i];
            #pragma unroll
            for (int jj = 0; jj < 8; ++jj) {
                const float* wr = Wm1 + (size_t)(cb + jj) * (2 * HID) + which * HID
                                + ch * 64 + kt * 8;
                acc[jj] += tv[0]*wr[0] + tv[1]*wr[1] + tv[2]*wr[2] + tv[3]*wr[3]
                         + tv[4]*wr[4] + tv[5]*wr[5] + tv[6]*wr[6] + tv[7]*wr[7];
            }
        }
    }
    if (valid) {
        float* dst = (which ? Bs : As) + (size_t)g * MH + cb;
        float4 v0, v1;
        v0.x = acc[0]; v0.y = acc[1]; v0.z = acc[2]; v0.w = acc[3];
        v1.x = acc[4]; v1.y = acc[5]; v1.z = acc[6]; v1.w = acc[7];
        *(float4*)(dst + 0) = v0;
        *(float4*)(dst + 4) = v1;
    }
}

// ===========================================================================
// k_edge_msg — 64 edges/block, register-tiled GEMV (unchanged from round 6).
// ===========================================================================
__global__ __launch_bounds__(256, 3) void k_edge_msg(
    const int* __restrict__ ei, const float* __restrict__ As, const float* __restrict__ Bs,
    const float* __restrict__ bm1, const float* __restrict__ Wm2, const float* __restrict__ bm2,
    float* __restrict__ P, float* __restrict__ M)
{
    __shared__ float plds[128 * 68];
    __shared__ float wm2s[16 * 68];
    __shared__ float fls[128 * 17];
    const int tid = threadIdx.x;
    const int w = tid >> 6, t = tid & 63;
    const int e0 = blockIdx.x * 64;

    for (int i = tid; i < 1024; i += 256)
        wm2s[(i >> 6) * 68 + (i & 63)] = Wm2[i];

    const float bm = bm1[t];

    for (int r = 0; r < 16; ++r) {
        const int el = w * 16 + r;
        const int e = e0 + el;
        const int src = ei[e], dst = ei[EE + e];
        float a_s = As[(size_t)src * MH + t];
        float b_d = Bs[(size_t)dst * MH + t];
        float a_d = As[(size_t)dst * MH + t];
        float b_s = Bs[(size_t)src * MH + t];
        plds[(el * 2 + 0) * 68 + t] = fmaxf(a_s + b_d + bm, 0.f);
        plds[(el * 2 + 1) * 68 + t] = fmaxf(a_d + b_s + bm, 0.f);
    }
    __syncthreads();

    {
        const int pg = tid & 31;
        const int jg = tid >> 5;
        const int j0 = jg * 2;
        float acc[4][2];
        #pragma unroll
        for (int i = 0; i < 4; ++i) { acc[i][0] = 0.f; acc[i][1] = 0.f; }

        const float4* w0 = (const float4*)&wm2s[(j0 + 0) * 68];
        const float4* w1 = (const float4*)&wm2s[(j0 + 1) * 68];
        const float4* p0 = (const float4*)&plds[(4 * pg + 0) * 68];
        const float4* p1 = (const float4*)&plds[(4 * pg + 1) * 68];
        const float4* p2 = (const float4*)&plds[(4 * pg + 2) * 68];
        const float4* p3 = (const float4*)&plds[(4 * pg + 3) * 68];

        #pragma unroll
        for (int k4 = 0; k4 < 16; ++k4) {
            float4 wv0 = w0[k4], wv1 = w1[k4];
            float4 a = p0[k4], b = p1[k4], c = p2[k4], d = p3[k4];
            acc[0][0] += a.x*wv0.x + a.y*wv0.y + a.z*wv0.z + a.w*wv0.w;
            acc[0][1] += a.x*wv1.x + a.y*wv1.y + a.z*wv1.z + a.w*wv1.w;
            acc[1][0] += b.x*wv0.x + b.y*wv0.y + b.z*wv0.z + b.w*wv0.w;
            acc[1][1] += b.x*wv1.x + b.y*wv1.y + b.z*wv1.z + b.w*wv1.w;
            acc[2][0] += c.x*wv0.x + c.y*wv0.y + c.z*wv0.z + c.w*wv0.w;
            acc[2][1] += c.x*wv1.x + c.y*wv1.y + c.z*wv1.z + c.w*wv1.w;
            acc[3][0] += d.x*wv0.x + d.y*wv0.y + d.z*wv0.z + d.w*wv0.w;
            acc[3][1] += d.x*wv1.x + d.y*wv1.y + d.z*wv1.z + d.w*wv1.w;
        }
        float bm2a = bm2[j0], bm2b = bm2[j0 + 1];
        #pragma unroll
        for (int i = 0; i < 4; ++i) {
            fls[(4 * pg + i) * 17 + j0]     = acc[i][0] + bm2a;
            fls[(4 * pg + i) * 17 + j0 + 1] = acc[i][1] + bm2b;
        }
    }
    __syncthreads();

    {
        const int el = tid >> 2, cg = tid & 3;
        const float* f0 = &fls[(el * 2 + 0) * 17];
        const float* f1 = &fls[(el * 2 + 1) * 17];
        float a0 = f0[0*4+cg], a1 = f0[1*4+cg], a2 = f0[2*4+cg], a3 = f0[3*4+cg];
        float b0 = f1[0*4+cg], b1 = f1[1*4+cg], b2 = f1[2*4+cg], b3 = f1[3*4+cg];
        float4 pp, qq, rr;
        {
            float c0, c1, c2, c3;
            c0 = f1[0]; c1 = f1[4]; c2 = f1[8]; c3 = f1[12];
            pp.x = a0*c0 + a1*c1 + a2*c2 + a3*c3;
            rr.x = b0*c0 + b1*c1 + b2*c2 + b3*c3;
            c0 = f1[1]; c1 = f1[5]; c2 = f1[9]; c3 = f1[13];
            pp.y = a0*c0 + a1*c1 + a2*c2 + a3*c3;
            rr.y = b0*c0 + b1*c1 + b2*c2 + b3*c3;
            c0 = f1[2]; c1 = f1[6]; c2 = f1[10]; c3 = f1[14];
            pp.z = a0*c0 + a1*c1 + a2*c2 + a3*c3;
            rr.z = b0*c0 + b1*c1 + b2*c2 + b3*c3;
            c0 = f1[3]; c1 = f1[7]; c2 = f1[11]; c3 = f1[15];
            pp.w = a0*c0 + a1*c1 + a2*c2 + a3*c3;
            rr.w = b0*c0 + b1*c1 + b2*c2 + b3*c3;
            c0 = f0[0]; c1 = f0[4]; c2 = f0[8]; c3 = f0[12];
            qq.x = a0*c0 + a1*c1 + a2*c2 + a3*c3;
            c0 = f0[1]; c1 = f0[5]; c2 = f0[9]; c3 = f0[13];
            qq.y = a0*c0 + a1*c1 + a2*c2 + a3*c3;
            c0 = f0[2]; c1 = f0[6]; c2 = f0[10]; c3 = f0[14];
            qq.z = a0*c0 + a1*c1 + a2*c2 + a3*c3;
            c0 = f0[3]; c1 = f0[7]; c2 = f0[11]; c3 = f0[15];
            qq.w = a0*c0 + a1*c1 + a2*c2 + a3*c3;
        }
        const int eg = e0 + el;
        *(float4*)(P + (size_t)eg * 16 + cg * 4) = pp;
        const int s2 = ei[eg], d2 = ei[EE + eg];
        float* ms = M + (size_t)s2 * 16 + cg * 4;
        float* md = M + (size_t)d2 * 16 + cg * 4;
        atomicAdd(ms + 0, qq.x); atomicAdd(ms + 1, qq.y);
        atomicAdd(ms + 2, qq.z); atomicAdd(ms + 3, qq.w);
        atomicAdd(md + 0, rr.x); atomicAdd(md + 1, rr.y);
        atomicAdd(md + 2, rr.z); atomicAdd(md + 3, rr.w);
    }
}

// ===========================================================================
// k_node_H — H0 = (Wd1.T @ xb) @ Wd2.T per node.
// ===========================================================================
__global__ __launch_bounds__(256) void k_node_H(
    const float* __restrict__ xb,
    const float* __restrict__ Wd1l, const float* __restrict__ Wd2l,
    float* __restrict__ H)
{
    __shared__ float wt[64][68];
    __shared__ float tl[4][4][64];
    const int tid = threadIdx.x;
    const int w = tid >> 6, t = tid & 63;

    for (int i = tid; i < 4096; i += 256) wt[i >> 6][i & 63] = Wd2l[i];
    float wd1[16];
    #pragma unroll
    for (int i = 0; i < 16; ++i) wd1[i] = Wd1l[i];
    __syncthreads();

    for (int rep = 0; rep < 4; ++rep) {
        const int n = blockIdx.x * 16 + w * 4 + rep;
        float xv[4];
        #pragma unroll
        for (int j = 0; j < 4; ++j) xv[j] = xb[(size_t)n * HID + j * 64 + t];
        #pragma unroll
        for (int i = 0; i < 4; ++i)
            tl[w][i][t] = wd1[0 + i] * xv[0] + wd1[4 + i] * xv[1] +
                          wd1[8 + i] * xv[2] + wd1[12 + i] * xv[3];
        __syncthreads();
        float a0 = 0, a1 = 0, a2 = 0, a3 = 0;
        #pragma unroll
        for (int f = 0; f < 64; f += 4) {
            float4 wv = *(const float4*)&wt[t][f];
            float4 t0 = *(const float4*)&tl[w][0][f];
            float4 t1 = *(const float4*)&tl[w][1][f];
            float4 t2 = *(const float4*)&tl[w][2][f];
            float4 t3 = *(const float4*)&tl[w][3][f];
            a0 += t0.x * wv.x + t0.y * wv.y + t0.z * wv.z + t0.w * wv.w;
            a1 += t1.x * wv.x + t1.y * wv.y + t1.z * wv.z + t1.w * wv.w;
            a2 += t2.x * wv.x + t2.y * wv.y + t2.z * wv.z + t2.w * wv.w;
            a3 += t3.x * wv.x + t3.y * wv.y + t3.z * wv.z + t3.w * wv.w;
        }
        __syncthreads();
        size_t base = (size_t)n * HID + t;
        H[base + 0 * 64] = a0;
        H[base + 1 * 64] = a1;
        H[base + 2 * 64] = a2;
        H[base + 3 * 64] = a3;
    }
}

// ===========================================================================
// Shared incidence-accumulate helper: acc -= P_e(^T) @ H[other], 2x unrolled.
// inc2 gives `other` directly (no ei hop). Branches are wave-uniform.
// ===========================================================================
__device__ __forceinline__ void sheaf_gather(
    const int* __restrict__ inc, const int* __restrict__ inc2,
    const float* __restrict__ P, const float* __restrict__ Hin,
    int p0, int p1, int t, float acc[4])
{
    int p = p0;
    for (; p + 2 <= p1; p += 2) {
        int vA = inc[p],     oA = inc2[p];
        int vB = inc[p + 1], oB = inc2[p + 1];
        const float* HoApt = Hin + (size_t)oA * HID + t;
        const float* HoBpt = Hin + (size_t)oB * HID + t;
        float hA0 = HoApt[0], hA1 = HoApt[64], hA2 = HoApt[128], hA3 = HoApt[192];
        float hB0 = HoBpt[0], hB1 = HoBpt[64], hB2 = HoBpt[128], hB3 = HoBpt[192];
        const float* PA = P + (size_t)(vA >> 1) * 16;
        const float* PB = P + (size_t)(vB >> 1) * 16;
        if (!(vA & 1)) {
            #pragma unroll
            for (int j = 0; j < 4; ++j)
                acc[j] -= PA[j*4+0]*hA0 + PA[j*4+1]*hA1 + PA[j*4+2]*hA2 + PA[j*4+3]*hA3;
        } else {
            #pragma unroll
            for (int j = 0; j < 4; ++j)
                acc[j] -= PA[0*4+j]*hA0 + PA[1*4+j]*hA1 + PA[2*4+j]*hA2 + PA[3*4+j]*hA3;
        }
        if (!(vB & 1)) {
            #pragma unroll
            for (int j = 0; j < 4; ++j)
                acc[j] -= PB[j*4+0]*hB0 + PB[j*4+1]*hB1 + PB[j*4+2]*hB2 + PB[j*4+3]*hB3;
        } else {
            #pragma unroll
            for (int j = 0; j < 4; ++j)
                acc[j] -= PB[0*4+j]*hB0 + PB[1*4+j]*hB1 + PB[2*4+j]*hB2 + PB[3*4+j]*hB3;
        }
    }
    if (p < p1) {
        int v = inc[p], o = inc2[p];
        const float* Hop = Hin + (size_t)o * HID + t;
        float h0 = Hop[0], h1 = Hop[64], h2 = Hop[128], h3 = Hop[192];
        const float* Pe = P + (size_t)(v >> 1) * 16;
        if (!(v & 1)) {
            #pragma unroll
            for (int j = 0; j < 4; ++j)
                acc[j] -= Pe[j*4+0]*h0 + Pe[j*4+1]*h1 + Pe[j*4+2]*h2 + Pe[j*4+3]*h3;
        } else {
            #pragma unroll
            for (int j = 0; j < 4; ++j)
                acc[j] -= Pe[0*4+j]*h0 + Pe[1*4+j]*h1 + Pe[2*4+j]*h2 + Pe[3*4+j]*h3;
        }
    }
}

// ===========================================================================
// k_sheaf0 — layer 0: LH gather + xb update + fused next-layer H (LDS).
// ===========================================================================
__global__ __launch_bounds__(256) void k_sheaf0(
    const int* __restrict__ inc, const int* __restrict__ inc2, const int* __restrict__ off,
    const float* __restrict__ P, const float* __restrict__ M,
    const float* __restrict__ Hin, float* __restrict__ h, float* __restrict__ Hout,
    const float* __restrict__ Wd1l, const float* __restrict__ Wd2l)
{
    __shared__ float wt[64][68];
    __shared__ float tl[4][4][64];
    const int tid = threadIdx.x;
    const int w = tid >> 6, t = tid & 63;

    for (int i = tid; i < 4096; i += 256) wt[i >> 6][i & 63] = Wd2l[i];
    float wd1[16];
    #pragma unroll
    for (int i = 0; i < 16; ++i) wd1[i] = Wd1l[i];
    __syncthreads();

    const int n = blockIdx.x * 4 + w;
    float Hn[4];
    #pragma unroll
    for (int k = 0; k < 4; ++k) Hn[k] = Hin[(size_t)n * HID + k * 64 + t];
    float Mn[16];
    #pragma unroll
    for (int c = 0; c < 16; ++c) Mn[c] = M[(size_t)n * 16 + c];

    float acc[4];
    #pragma unroll
    for (int j = 0; j < 4; ++j)
        acc[j] = Mn[j*4+0]*Hn[0] + Mn[j*4+1]*Hn[1] + Mn[j*4+2]*Hn[2] + Mn[j*4+3]*Hn[3];

    sheaf_gather(inc, inc2, P, Hin, off[n], off[n + 1], t, acc);

    float xv[4];
    #pragma unroll
    for (int j = 0; j < 4; ++j) {
        size_t idx = (size_t)n * HID + j * 64 + t;
        float vv = h[idx] - fmaxf(acc[j], 0.f);
        h[idx] = vv;
        xv[j] = vv;
    }

    #pragma unroll
    for (int i = 0; i < 4; ++i)
        tl[w][i][t] = wd1[0 + i] * xv[0] + wd1[4 + i] * xv[1] +
                      wd1[8 + i] * xv[2] + wd1[12 + i] * xv[3];
    __syncthreads();
    float a0 = 0, a1 = 0, a2 = 0, a3 = 0;
    #pragma unroll
    for (int f = 0; f < 64; f += 4) {
        float4 wv = *(const float4*)&wt[t][f];
        float4 t0 = *(const float4*)&tl[w][0][f];
        float4 t1 = *(const float4*)&tl[w][1][f];
        float4 t2 = *(const float4*)&tl[w][2][f];
        float4 t3 = *(const float4*)&tl[w][3][f];
        a0 += t0.x * wv.x + t0.y * wv.y + t0.z * wv.z + t0.w * wv.w;
        a1 += t1.x * wv.x + t1.y * wv.y + t1.z * wv.z + t1.w * wv.w;
        a2 += t2.x * wv.x + t2.y * wv.y + t2.z * wv.z + t2.w * wv.w;
        a3 += t3.x * wv.x + t3.y * wv.y + t3.z * wv.z + t3.w * wv.w;
    }
    size_t base = (size_t)n * HID + t;
    Hout[base + 0 * 64] = a0;
    Hout[base + 1 * 64] = a1;
    Hout[base + 2 * 64] = a2;
    Hout[base + 3 * 64] = a3;
}

// ===========================================================================
// k_sheaf1 — layer 1: LH gather + xb update only. ZERO LDS (occupancy).
// ===========================================================================
__global__ __launch_bounds__(256) void k_sheaf1(
    const int* __restrict__ inc, const int* __restrict__ inc2, const int* __restrict__ off,
    const float* __restrict__ P, const float* __restrict__ M,
    const float* __restrict__ Hin, float* __restrict__ h)
{
    const int tid = threadIdx.x;
    const int w = tid >> 6, t = tid & 63;
    const int n = blockIdx.x * 4 + w;

    float Hn[4];
    #pragma unroll
    for (int k = 0; k < 4; ++k) Hn[k] = Hin[(size_t)n * HID + k * 64 + t];
    float Mn[16];
    #pragma unroll
    for (int c = 0; c < 16; ++c) Mn[c] = M[(size_t)n * 16 + c];

    float acc[4];
    #pragma unroll
    for (int j = 0; j < 4; ++j)
        acc[j] = Mn[j*4+0]*Hn[0] + Mn[j*4+1]*Hn[1] + Mn[j*4+2]*Hn[2] + Mn[j*4+3]*Hn[3];

    sheaf_gather(inc, inc2, P, Hin, off[n], off[n + 1], t, acc);

    #pragma unroll
    for (int j = 0; j < 4; ++j) {
        size_t idx = (size_t)n * HID + j * 64 + t;
        h[idx] = h[idx] - fmaxf(acc[j], 0.f);
    }
}

// ===========================================================================
// k_out1: t1o = relu(xb @ Wo1.T + bo1).  grid (N/64, 4).
// ===========================================================================
__global__ __launch_bounds__(256, 4) void k_out1(
    const float* __restrict__ xb, const float* __restrict__ Wo1, const float* __restrict__ bo1,
    float* __restrict__ t1o)
{
    __shared__ float xr[64 * 129];
    const int tid  = threadIdx.x;
    const int w    = __builtin_amdgcn_readfirstlane(tid >> 6);
    const int lane = tid & 63;
    const int node0 = blockIdx.x * 64;
    const int cbase = blockIdx.y * 16 + w * 4;
    const int g = min(node0 + lane, NN - 1);
    const bool valid = (node0 + lane) < NN;

    float acc[4] = {0.f, 0.f, 0.f, 0.f};

    for (int j = 0; j < 2; ++j) {
        __syncthreads();
        for (int i = tid; i < 2048; i += 256) {
            int n = i >> 5, k4 = i & 31;
            int gr = min(node0 + n, NN - 1);
            float4 v = ((const float4*)xb)[(size_t)gr * 64 + j * 32 + k4];
            float* d = &xr[n * 129 + k4 * 4];
            d[0] = v.x; d[1] = v.y; d[2] = v.z; d[3] = v.w;
        }
        __syncthreads();
        for (int kt = 0; kt < 32; ++kt) {
            float x0 = xr[lane * 129 + kt * 4 + 0];
            float x1 = xr[lane * 129 + kt * 4 + 1];
            float x2 = xr[lane * 129 + kt * 4 + 2];
            float x3 = xr[lane * 129 + kt * 4 + 3];
            #pragma unroll
            for (int cc = 0; cc < 4; ++cc) {
                const float* wr = Wo1 + (size_t)(cbase + cc) * HID + j * 128 + kt * 4;
                acc[cc] += x0 * wr[0] + x1 * wr[1] + x2 * wr[2] + x3 * wr[3];
            }
        }
    }
    if (valid) {
        float4 v;
        v.x = fmaxf(acc[0] + bo1[cbase + 0], 0.f);
        v.y = fmaxf(acc[1] + bo1[cbase + 1], 0.f);
        v.z = fmaxf(acc[2] + bo1[cbase + 2], 0.f);
        v.w = fmaxf(acc[3] + bo1[cbase + 3], 0.f);
        *(float4*)(t1o + (size_t)g * MH + cbase) = v;
    }
}

// ===========================================================================
// k_out2: out = t1o @ Wo2.T + bo2.
// ===========================================================================
__global__ __launch_bounds__(256, 4) void k_out2(
    const float* __restrict__ t1o, const float* __restrict__ Wo2, const float* __restrict__ bo2,
    float* __restrict__ out)
{
    __shared__ float ts[64 * 65];
    const int tid  = threadIdx.x;
    const int lane = tid & 63;
    const int node0 = blockIdx.x * 64;
    const int g = min(node0 + lane, NN - 1);
    const bool valid = (node0 + lane) < NN;

    for (int i = tid; i < 1024; i += 256) {
        int n = i >> 4, k4 = i & 15;
        int gr = min(node0 + n, NN - 1);
        float4 v = ((const float4*)t1o)[(size_t)gr * 16 + k4];
        float* d = &ts[n * 65 + k4 * 4];
        d[0] = v.x; d[1] = v.y; d[2] = v.z; d[3] = v.w;
    }
    __syncthreads();

    float acc[16];
    #pragma unroll
    for (int i = 0; i < 16; ++i) acc[i] = 0.f;
    for (int kt = 0; kt < 8; ++kt) {
        float tv[8];
        #pragma unroll
        for (int i = 0; i < 8; ++i) tv[i] = ts[lane * 65 + kt * 8 + i];
        #pragma unroll
        for (int jj = 0; jj < 16; ++jj) {
            const float* wr = Wo2 + (size_t)jj * MH + kt * 8;
            acc[jj] += tv[0]*wr[0] + tv[1]*wr[1] + tv[2]*wr[2] + tv[3]*wr[3]
                     + tv[4]*wr[4] + tv[5]*wr[5] + tv[6]*wr[6] + tv[7]*wr[7];
        }
    }
    if (valid) {
        float* op = out + (size_t)g * OUT_D;
        #pragma unroll
        for (int c4 = 0; c4 < 4; ++c4) {
            float4 v;
            v.x = acc[c4*4+0] + bo2[c4*4+0];
            v.y = acc[c4*4+1] + bo2[c4*4+1];
            v.z = acc[c4*4+2] + bo2[c4*4+2];
            v.w = acc[c4*4+3] + bo2[c4*4+3];
            *(float4*)(op + c4 * 4) = v;
        }
    }
}

// ---------------------------------------------------------------------------
// Workspace layout (~89.2 MB): round-6 layout + inc2 (2E ints).
// t1=H0, t1o=H1 aliases.
// ---------------------------------------------------------------------------
extern "C" void kernel_launch(void* const* d_in, const int* in_sizes, int n_in,
                              void* d_out, int out_size, void* d_ws, size_t ws_size,
                              hipStream_t stream)
{
    const float* x    = (const float*)d_in[0];
    const int*   ei   = (const int*)d_in[1];
    const float* Win1 = (const float*)d_in[2];
    const float* bin1 = (const float*)d_in[3];
    const float* Win2 = (const float*)d_in[4];
    const float* bin2 = (const float*)d_in[5];
    const float* Wm1  = (const float*)d_in[6];
    const float* bm1  = (const float*)d_in[7];
    const float* Wm2  = (const float*)d_in[8];
    const float* bm2  = (const float*)d_in[9];
    const float* Wd1  = (const float*)d_in[10];
    const float* Wd2  = (const float*)d_in[11];
    const float* Wo1  = (const float*)d_in[12];
    const float* bo1  = (const float*)d_in[13];
    const float* Wo2  = (const float*)d_in[14];
    const float* bo2  = (const float*)d_in[15];
    float* out = (float*)d_out;

    float* ws = (float*)d_ws;
    float* h  = ws;                            // N*256
    float* As = h  + (size_t)NN * HID;         // N*64
    float* Bs = As + (size_t)NN * MH;          // N*64
    float* H0 = Bs + (size_t)NN * MH;          // N*256
    float* H1 = H0 + (size_t)NN * HID;         // N*256
    float* P  = H1 + (size_t)NN * HID;         // E*16
    float* M  = P  + (size_t)EE * 16;          // N*16
    int* deg    = (int*)(M + (size_t)NN * 16); // N
    int* off    = deg + NN;                    // N+1
    int* cursor = off + NN + 1;                // N
    int* inc    = cursor + NN;                 // 2E
    int* inc2   = inc + 2 * EE;                // 2E
    float* t1  = H0;                           // alias
    float* t1o = H1;                           // alias

    const int NB = (NN + 63) / 64;             // 313

    // CSR build + M zero
    hipMemsetAsync(deg, 0, NN * sizeof(int), stream);
    hipMemsetAsync(M, 0, (size_t)NN * 16 * sizeof(float), stream);
    k_deg<<<(EE + 255) / 256, 256, 0, stream>>>(ei, deg);
    k_scan<<<1, 256, 0, stream>>>(deg, off, cursor);
    k_scatter<<<(EE + 255) / 256, 256, 0, stream>>>(ei, cursor, inc, inc2);

    // node MLP + per-edge P/Q/R
    k_mlp1<<<dim3(NB, 4), 256, 0, stream>>>(x, Win1, bin1, t1);
    k_mlp2<<<dim3(NB, 4), 256, 0, stream>>>(t1, Win2, bin2, h);
    k_mlp3<<<dim3(NB, 4), 256, 0, stream>>>(h, Wm1, As, Bs);
    k_edge_msg<<<EE / 64, 256, 0, stream>>>(ei, As, Bs, bm1, Wm2, bm2, P, M);

    // diffusion
    k_node_H<<<NN / 16, 256, 0, stream>>>(h, Wd1, Wd2, H0);
    k_sheaf0<<<NN / 4, 256, 0, stream>>>(inc, inc2, off, P, M, H0, h, H1,
                                         Wd1 + 16, Wd2 + 4096);
    k_sheaf1<<<NN / 4, 256, 0, stream>>>(inc, inc2, off, P, M, H1, h);

    // output MLP
    k_out1<<<dim3(NB, 4), 256, 0, stream>>>(h, Wo1, bo1, t1o);
    k_out2<<<NB, 256, 0, stream>>>(t1o, Wo2, bo2, out);
}

// Round 9
// 640.016 us; speedup vs baseline: 3.1826x; 1.0112x over previous
//
#include <hip/hip_runtime.h>

constexpr int NN   = 20000;
constexpr int EE   = 200000;
constexpr int IN_D = 500;
constexpr int HID  = 256;
constexpr int OUT_D= 16;
constexpr int MH   = 64;

// ===========================================================================
// CSR incidence build. inc entry = edge*2 + is_dst; inc2 entry = other node.
// ===========================================================================
__global__ __launch_bounds__(256) void k_deg(const int* __restrict__ ei, int* __restrict__ deg)
{
    int e = blockIdx.x * 256 + threadIdx.x;
    if (e < EE) {
        atomicAdd(deg + ei[e], 1);
        atomicAdd(deg + ei[EE + e], 1);
    }
}

__global__ __launch_bounds__(256) void k_scan(const int* __restrict__ deg,
                                              int* __restrict__ off, int* __restrict__ cursor)
{
    __shared__ int part[256];
    __shared__ int base[256];
    const int tid = threadIdx.x;
    const int CH = (NN + 255) / 256;
    int s = 0;
    for (int i = 0; i < CH; ++i) { int n = tid * CH + i; if (n < NN) s += deg[n]; }
    part[tid] = s;
    __syncthreads();
    if (tid == 0) { int r = 0; for (int i = 0; i < 256; ++i) { base[i] = r; r += part[i]; } }
    __syncthreads();
    int r = base[tid];
    for (int i = 0; i < CH; ++i) {
        int n = tid * CH + i;
        if (n < NN) { off[n] = r; cursor[n] = r; r += deg[n]; }
    }
    if (tid == 255) off[NN] = r;
}

__global__ __launch_bounds__(256) void k_scatter(const int* __restrict__ ei,
                                                 int* __restrict__ cursor,
                                                 int* __restrict__ inc, int* __restrict__ inc2)
{
    int e = blockIdx.x * 256 + threadIdx.x;
    if (e < EE) {
        int s = ei[e], d = ei[EE + e];
        int p = atomicAdd(cursor + s, 1); inc[p] = e * 2;     inc2[p] = d;
        p = atomicAdd(cursor + d, 1);     inc[p] = e * 2 + 1; inc2[p] = s;
    }
}

// ===========================================================================
// k_mlp1: t1 = relu(x @ Win1.T + bin1).  grid (N/64, 4).
// ===========================================================================
__global__ __launch_bounds__(256, 4) void k_mlp1(
    const float* __restrict__ x, const float* __restrict__ Win1, const float* __restrict__ bin1,
    float* __restrict__ t1)
{
    __shared__ float xs[64 * 101];
    const int tid  = threadIdx.x;
    const int w    = __builtin_amdgcn_readfirstlane(tid >> 6);
    const int lane = tid & 63;
    const int node0 = blockIdx.x * 64;
    const int cbase = blockIdx.y * 16 + w * 4;
    const int g = min(node0 + lane, NN - 1);
    const bool valid = (node0 + lane) < NN;

    float acc[4] = {0.f, 0.f, 0.f, 0.f};

    for (int j = 0; j < 5; ++j) {
        __syncthreads();
        for (int i = tid; i < 1600; i += 256) {
            int n = i / 25, k4 = i % 25;
            int gr = min(node0 + n, NN - 1);
            float4 v = ((const float4*)x)[(size_t)gr * 125 + j * 25 + k4];
            float* d = &xs[n * 101 + k4 * 4];
            d[0] = v.x; d[1] = v.y; d[2] = v.z; d[3] = v.w;
        }
        __syncthreads();
        for (int kt = 0; kt < 25; ++kt) {
            float x0 = xs[lane * 101 + kt * 4 + 0];
            float x1 = xs[lane * 101 + kt * 4 + 1];
            float x2 = xs[lane * 101 + kt * 4 + 2];
            float x3 = xs[lane * 101 + kt * 4 + 3];
            #pragma unroll
            for (int cc = 0; cc < 4; ++cc) {
                const float* wr = Win1 + (size_t)(cbase + cc) * IN_D + j * 100 + kt * 4;
                acc[cc] += x0 * wr[0] + x1 * wr[1] + x2 * wr[2] + x3 * wr[3];
            }
        }
    }
    if (valid) {
        float4 v;
        v.x = fmaxf(acc[0] + bin1[cbase + 0], 0.f);
        v.y = fmaxf(acc[1] + bin1[cbase + 1], 0.f);
        v.z = fmaxf(acc[2] + bin1[cbase + 2], 0.f);
        v.w = fmaxf(acc[3] + bin1[cbase + 3], 0.f);
        *(float4*)(t1 + (size_t)g * MH + cbase) = v;
    }
}

// ===========================================================================
// k_mlp2: h = t1 @ Win2.T + bin2.  grid (N/64, 4).
// ===========================================================================
__global__ __launch_bounds__(256, 4) void k_mlp2(
    const float* __restrict__ t1, const float* __restrict__ Win2, const float* __restrict__ bin2,
    float* __restrict__ h)
{
    __shared__ float ts[64 * 65];
    const int tid  = threadIdx.x;
    const int w    = __builtin_amdgcn_readfirstlane(tid >> 6);
    const int lane = tid & 63;
    const int node0 = blockIdx.x * 64;
    const int cbase = blockIdx.y * 64 + w * 16;
    const int g = min(node0 + lane, NN - 1);
    const bool valid = (node0 + lane) < NN;

    for (int i = tid; i < 1024; i += 256) {
        int n = i >> 4, k4 = i & 15;
        int gr = min(node0 + n, NN - 1);
        float4 v = ((const float4*)t1)[(size_t)gr * 16 + k4];
        float* d = &ts[n * 65 + k4 * 4];
        d[0] = v.x; d[1] = v.y; d[2] = v.z; d[3] = v.w;
    }
    __syncthreads();

    float acc[16];
    #pragma unroll
    for (int i = 0; i < 16; ++i) acc[i] = 0.f;
    for (int kt = 0; kt < 8; ++kt) {
        float tv[8];
        #pragma unroll
        for (int i = 0; i < 8; ++i) tv[i] = ts[lane * 65 + kt * 8 + i];
        #pragma unroll
        for (int cc = 0; cc < 16; ++cc) {
            const float* wr = Win2 + (size_t)(cbase + cc) * MH + kt * 8;
            acc[cc] += tv[0]*wr[0] + tv[1]*wr[1] + tv[2]*wr[2] + tv[3]*wr[3]
                     + tv[4]*wr[4] + tv[5]*wr[5] + tv[6]*wr[6] + tv[7]*wr[7];
        }
    }
    if (valid) {
        float* hp = h + (size_t)g * HID + cbase;
        #pragma unroll
        for (int c4 = 0; c4 < 4; ++c4) {
            float4 v;
            v.x = acc[c4*4+0] + bin2[cbase + c4*4+0];
            v.y = acc[c4*4+1] + bin2[cbase + c4*4+1];
            v.z = acc[c4*4+2] + bin2[cbase + c4*4+2];
            v.w = acc[c4*4+3] + bin2[cbase + c4*4+3];
            *(float4*)(hp + c4 * 4) = v;
        }
    }
}

// ===========================================================================
// k_mlp3: As = h @ Wa.T, Bs = h @ Wb.T.  grid (N/64, 4).
// ===========================================================================
__global__ __launch_bounds__(256, 4) void k_mlp3(
    const float* __restrict__ h, const float* __restrict__ Wm1,
    float* __restrict__ As, float* __restrict__ Bs)
{
    __shared__ float hsm[64 * 65];
    const int tid  = threadIdx.x;
    const int w    = __builtin_amdgcn_readfirstlane(tid >> 6);
    const int lane = tid & 63;
    const int node0 = blockIdx.x * 64;
    const int vcb = blockIdx.y * 32 + w * 8;
    const int which = vcb >> 6;
    const int cb = vcb & 63;
    const int g = min(node0 + lane, NN - 1);
    const bool valid = (node0 + lane) < NN;

    float acc[8];
    #pragma unroll
    for (int i = 0; i < 8; ++i) acc[i] = 0.f;

    for (int ch = 0; ch < 4; ++ch) {
        __syncthreads();
        for (int i = tid; i < 1024; i += 256) {
            int n = i >> 4, k4 = i & 15;
            int gr = min(node0 + n, NN - 1);
            float4 v = ((const float4*)h)[(size_t)gr * 64 + ch * 16 + k4];
            float* d = &hsm[n * 65 + k4 * 4];
            d[0] = v.x; d[1] = v.y; d[2] = v.z; d[3] = v.w;
        }
        __syncthreads();
        for (int kt = 0; kt < 8; ++kt) {
            float tv[8];
            #pragma unroll
            for (int i = 0; i < 8; ++i) tv[i] = hsm[lane * 65 + kt * 8 + i];
            #pragma unroll
            for (int jj = 0; jj < 8; ++jj) {
                const float* wr = Wm1 + (size_t)(cb + jj) * (2 * HID) + which * HID
                                + ch * 64 + kt * 8;
                acc[jj] += tv[0]*wr[0] + tv[1]*wr[1] + tv[2]*wr[2] + tv[3]*wr[3]
                         + tv[4]*wr[4] + tv[5]*wr[5] + tv[6]*wr[6] + tv[7]*wr[7];
            }
        }
    }
    if (valid) {
        float* dst = (which ? Bs : As) + (size_t)g * MH + cb;
        float4 v0, v1;
        v0.x = acc[0]; v0.y = acc[1]; v0.z = acc[2]; v0.w = acc[3];
        v1.x = acc[4]; v1.y = acc[5]; v1.z = acc[6]; v1.w = acc[7];
        *(float4*)(dst + 0) = v0;
        *(float4*)(dst + 4) = v1;
    }
}

// ===========================================================================
// k_edge_msg — 64 edges/block.
// plds: 128 rows x 64 floats, CHUNK-ROTATED: original 16B-chunk k of row r
// lives at slot (k + (r>>2)) & 15. Row pitch 64 -> phase-2 b128 reads at
// fixed k4 start at bank-slot (k4+pg)&7, 8 lanes/slot = conflict-free.
// fls aliases plds (extra barrier). LDS 36.3 KB -> 4 blocks/CU.
// ===========================================================================
__global__ __launch_bounds__(256, 4) void k_edge_msg(
    const int* __restrict__ ei, const float* __restrict__ As, const float* __restrict__ Bs,
    const float* __restrict__ bm1, const float* __restrict__ Wm2, const float* __restrict__ bm2,
    float* __restrict__ P, float* __restrict__ M)
{
    __shared__ float smem[128 * 64];   // plds, later aliased as fls[128*17]
    __shared__ float wm2s[16 * 68];
    const int tid = threadIdx.x;
    const int w = tid >> 6, t = tid & 63;
    const int e0 = blockIdx.x * 64;

    for (int i = tid; i < 1024; i += 256)
        wm2s[(i >> 6) * 68 + (i & 63)] = Wm2[i];

    const float bm = bm1[t];
    const int tc = t >> 2, tr = t & 3;   // chunk/remainder of this lane's k

    // phase 1: 16 edges per wave; swizzled scatter into plds
    for (int r = 0; r < 16; ++r) {
        const int el = w * 16 + r;
        const int e = e0 + el;
        const int src = ei[e], dst = ei[EE + e];
        float a_s = As[(size_t)src * MH + t];
        float b_d = Bs[(size_t)dst * MH + t];
        float a_d = As[(size_t)dst * MH + t];
        float b_s = Bs[(size_t)src * MH + t];
        const int row0 = el * 2, row1 = el * 2 + 1;
        // rotation amount row>>2 is wave-uniform per store (el fixed)
        smem[row0 * 64 + (((tc) + (row0 >> 2)) & 15) * 4 + tr] = fmaxf(a_s + b_d + bm, 0.f);
        smem[row1 * 64 + (((tc) + (row1 >> 2)) & 15) * 4 + tr] = fmaxf(a_d + b_s + bm, 0.f);
    }
    __syncthreads();

    // phase 2: register-tiled GEMV; thread = (pg, jg): rows 4pg..4pg+3, j = 2jg,2jg+1
    float acc[4][2];
    {
        const int pg = tid & 31;
        const int jg = tid >> 5;
        const int j0 = jg * 2;
        #pragma unroll
        for (int i = 0; i < 4; ++i) { acc[i][0] = 0.f; acc[i][1] = 0.f; }

        const float4* w0 = (const float4*)&wm2s[(j0 + 0) * 68];
        const float4* w1 = (const float4*)&wm2s[(j0 + 1) * 68];
        const float4* p0 = (const float4*)&smem[(4 * pg + 0) * 64];
        const float4* p1 = (const float4*)&smem[(4 * pg + 1) * 64];
        const float4* p2 = (const float4*)&smem[(4 * pg + 2) * 64];
        const float4* p3 = (const float4*)&smem[(4 * pg + 3) * 64];

        #pragma unroll
        for (int k4 = 0; k4 < 16; ++k4) {
            const int ch = (k4 + pg) & 15;   // rotated slot of original chunk k4
            float4 wv0 = w0[k4], wv1 = w1[k4];
            float4 a = p0[ch], b = p1[ch], c = p2[ch], d = p3[ch];
            acc[0][0] += a.x*wv0.x + a.y*wv0.y + a.z*wv0.z + a.w*wv0.w;
            acc[0][1] += a.x*wv1.x + a.y*wv1.y + a.z*wv1.z + a.w*wv1.w;
            acc[1][0] += b.x*wv0.x + b.y*wv0.y + b.z*wv0.z + b.w*wv0.w;
            acc[1][1] += b.x*wv1.x + b.y*wv1.y + b.z*wv1.z + b.w*wv1.w;
            acc[2][0] += c.x*wv0.x + c.y*wv0.y + c.z*wv0.z + c.w*wv0.w;
            acc[2][1] += c.x*wv1.x + c.y*wv1.y + c.z*wv1.z + c.w*wv1.w;
            acc[3][0] += d.x*wv0.x + d.y*wv0.y + d.z*wv0.z + d.w*wv0.w;
            acc[3][1] += d.x*wv1.x + d.y*wv1.y + d.z*wv1.z + d.w*wv1.w;
        }
    }
    __syncthreads();   // all plds reads done; smem now reusable as fls

    float* fls = smem;  // 128 rows x 17
    {
        const int pg = tid & 31;
        const int jg = tid >> 5;
        const int j0 = jg * 2;
        float bm2a = bm2[j0], bm2b = bm2[j0 + 1];
        #pragma unroll
        for (int i = 0; i < 4; ++i) {
            fls[(4 * pg + i) * 17 + j0]     = acc[i][0] + bm2a;
            fls[(4 * pg + i) * 17 + j0 + 1] = acc[i][1] + bm2b;
        }
    }
    __syncthreads();

    // phase 3: thread = (edge el, row cg); P row write + M atomics
    {
        const int el = tid >> 2, cg = tid & 3;
        const float* f0 = &fls[(el * 2 + 0) * 17];
        const float* f1 = &fls[(el * 2 + 1) * 17];
        float a0 = f0[0*4+cg], a1 = f0[1*4+cg], a2 = f0[2*4+cg], a3 = f0[3*4+cg];
        float b0 = f1[0*4+cg], b1 = f1[1*4+cg], b2 = f1[2*4+cg], b3 = f1[3*4+cg];
        float4 pp, qq, rr;
        {
            float c0, c1, c2, c3;
            c0 = f1[0]; c1 = f1[4]; c2 = f1[8]; c3 = f1[12];
            pp.x = a0*c0 + a1*c1 + a2*c2 + a3*c3;
            rr.x = b0*c0 + b1*c1 + b2*c2 + b3*c3;
            c0 = f1[1]; c1 = f1[5]; c2 = f1[9]; c3 = f1[13];
            pp.y = a0*c0 + a1*c1 + a2*c2 + a3*c3;
            rr.y = b0*c0 + b1*c1 + b2*c2 + b3*c3;
            c0 = f1[2]; c1 = f1[6]; c2 = f1[10]; c3 = f1[14];
            pp.z = a0*c0 + a1*c1 + a2*c2 + a3*c3;
            rr.z = b0*c0 + b1*c1 + b2*c2 + b3*c3;
            c0 = f1[3]; c1 = f1[7]; c2 = f1[11]; c3 = f1[15];
            pp.w = a0*c0 + a1*c1 + a2*c2 + a3*c3;
            rr.w = b0*c0 + b1*c1 + b2*c2 + b3*c3;
            c0 = f0[0]; c1 = f0[4]; c2 = f0[8]; c3 = f0[12];
            qq.x = a0*c0 + a1*c1 + a2*c2 + a3*c3;
            c0 = f0[1]; c1 = f0[5]; c2 = f0[9]; c3 = f0[13];
            qq.y = a0*c0 + a1*c1 + a2*c2 + a3*c3;
            c0 = f0[2]; c1 = f0[6]; c2 = f0[10]; c3 = f0[14];
            qq.z = a0*c0 + a1*c1 + a2*c2 + a3*c3;
            c0 = f0[3]; c1 = f0[7]; c2 = f0[11]; c3 = f0[15];
            qq.w = a0*c0 + a1*c1 + a2*c2 + a3*c3;
        }
        const int eg = e0 + el;
        *(float4*)(P + (size_t)eg * 16 + cg * 4) = pp;
        const int s2 = ei[eg], d2 = ei[EE + eg];
        float* ms = M + (size_t)s2 * 16 + cg * 4;
        float* md = M + (size_t)d2 * 16 + cg * 4;
        atomicAdd(ms + 0, qq.x); atomicAdd(ms + 1, qq.y);
        atomicAdd(ms + 2, qq.z); atomicAdd(ms + 3, qq.w);
        atomicAdd(md + 0, rr.x); atomicAdd(md + 1, rr.y);
        atomicAdd(md + 2, rr.z); atomicAdd(md + 3, rr.w);
    }
}

// ===========================================================================
// k_node_H — H0 = (Wd1.T @ xb) @ Wd2.T per node.
// ===========================================================================
__global__ __launch_bounds__(256) void k_node_H(
    const float* __restrict__ xb,
    const float* __restrict__ Wd1l, const float* __restrict__ Wd2l,
    float* __restrict__ H)
{
    __shared__ float wt[64][68];
    __shared__ float tl[4][4][64];
    const int tid = threadIdx.x;
    const int w = tid >> 6, t = tid & 63;

    for (int i = tid; i < 4096; i += 256) wt[i >> 6][i & 63] = Wd2l[i];
    float wd1[16];
    #pragma unroll
    for (int i = 0; i < 16; ++i) wd1[i] = Wd1l[i];
    __syncthreads();

    for (int rep = 0; rep < 4; ++rep) {
        const int n = blockIdx.x * 16 + w * 4 + rep;
        float xv[4];
        #pragma unroll
        for (int j = 0; j < 4; ++j) xv[j] = xb[(size_t)n * HID + j * 64 + t];
        #pragma unroll
        for (int i = 0; i < 4; ++i)
            tl[w][i][t] = wd1[0 + i] * xv[0] + wd1[4 + i] * xv[1] +
                          wd1[8 + i] * xv[2] + wd1[12 + i] * xv[3];
        __syncthreads();
        float a0 = 0, a1 = 0, a2 = 0, a3 = 0;
        #pragma unroll
        for (int f = 0; f < 64; f += 4) {
            float4 wv = *(const float4*)&wt[t][f];
            float4 t0 = *(const float4*)&tl[w][0][f];
            float4 t1 = *(const float4*)&tl[w][1][f];
            float4 t2 = *(const float4*)&tl[w][2][f];
            float4 t3 = *(const float4*)&tl[w][3][f];
            a0 += t0.x * wv.x + t0.y * wv.y + t0.z * wv.z + t0.w * wv.w;
            a1 += t1.x * wv.x + t1.y * wv.y + t1.z * wv.z + t1.w * wv.w;
            a2 += t2.x * wv.x + t2.y * wv.y + t2.z * wv.z + t2.w * wv.w;
            a3 += t3.x * wv.x + t3.y * wv.y + t3.z * wv.z + t3.w * wv.w;
        }
        __syncthreads();
        size_t base = (size_t)n * HID + t;
        H[base + 0 * 64] = a0;
        H[base + 1 * 64] = a1;
        H[base + 2 * 64] = a2;
        H[base + 3 * 64] = a3;
    }
}

// ===========================================================================
// Shared incidence-accumulate helper: acc -= P_e(^T) @ H[other], 2x unrolled.
// ===========================================================================
__device__ __forceinline__ void sheaf_gather(
    const int* __restrict__ inc, const int* __restrict__ inc2,
    const float* __restrict__ P, const float* __restrict__ Hin,
    int p0, int p1, int t, float acc[4])
{
    int p = p0;
    for (; p + 2 <= p1; p += 2) {
        int vA = inc[p],     oA = inc2[p];
        int vB = inc[p + 1], oB = inc2[p + 1];
        const float* HoApt = Hin + (size_t)oA * HID + t;
        const float* HoBpt = Hin + (size_t)oB * HID + t;
        float hA0 = HoApt[0], hA1 = HoApt[64], hA2 = HoApt[128], hA3 = HoApt[192];
        float hB0 = HoBpt[0], hB1 = HoBpt[64], hB2 = HoBpt[128], hB3 = HoBpt[192];
        const float* PA = P + (size_t)(vA >> 1) * 16;
        const float* PB = P + (size_t)(vB >> 1) * 16;
        if (!(vA & 1)) {
            #pragma unroll
            for (int j = 0; j < 4; ++j)
                acc[j] -= PA[j*4+0]*hA0 + PA[j*4+1]*hA1 + PA[j*4+2]*hA2 + PA[j*4+3]*hA3;
        } else {
            #pragma unroll
            for (int j = 0; j < 4; ++j)
                acc[j] -= PA[0*4+j]*hA0 + PA[1*4+j]*hA1 + PA[2*4+j]*hA2 + PA[3*4+j]*hA3;
        }
        if (!(vB & 1)) {
            #pragma unroll
            for (int j = 0; j < 4; ++j)
                acc[j] -= PB[j*4+0]*hB0 + PB[j*4+1]*hB1 + PB[j*4+2]*hB2 + PB[j*4+3]*hB3;
        } else {
            #pragma unroll
            for (int j = 0; j < 4; ++j)
                acc[j] -= PB[0*4+j]*hB0 + PB[1*4+j]*hB1 + PB[2*4+j]*hB2 + PB[3*4+j]*hB3;
        }
    }
    if (p < p1) {
        int v = inc[p], o = inc2[p];
        const float* Hop = Hin + (size_t)o * HID + t;
        float h0 = Hop[0], h1 = Hop[64], h2 = Hop[128], h3 = Hop[192];
        const float* Pe = P + (size_t)(v >> 1) * 16;
        if (!(v & 1)) {
            #pragma unroll
            for (int j = 0; j < 4; ++j)
                acc[j] -= Pe[j*4+0]*h0 + Pe[j*4+1]*h1 + Pe[j*4+2]*h2 + Pe[j*4+3]*h3;
        } else {
            #pragma unroll
            for (int j = 0; j < 4; ++j)
                acc[j] -= Pe[0*4+j]*h0 + Pe[1*4+j]*h1 + Pe[2*4+j]*h2 + Pe[3*4+j]*h3;
        }
    }
}

// ===========================================================================
// k_sheaf0 — layer 0: LH gather + xb update + fused next-layer H (LDS).
// ===========================================================================
__global__ __launch_bounds__(256) void k_sheaf0(
    const int* __restrict__ inc, const int* __restrict__ inc2, const int* __restrict__ off,
    const float* __restrict__ P, const float* __restrict__ M,
    const float* __restrict__ Hin, float* __restrict__ h, float* __restrict__ Hout,
    const float* __restrict__ Wd1l, const float* __restrict__ Wd2l)
{
    __shared__ float wt[64][68];
    __shared__ float tl[4][4][64];
    const int tid = threadIdx.x;
    const int w = tid >> 6, t = tid & 63;

    for (int i = tid; i < 4096; i += 256) wt[i >> 6][i & 63] = Wd2l[i];
    float wd1[16];
    #pragma unroll
    for (int i = 0; i < 16; ++i) wd1[i] = Wd1l[i];
    __syncthreads();

    const int n = blockIdx.x * 4 + w;
    float Hn[4];
    #pragma unroll
    for (int k = 0; k < 4; ++k) Hn[k] = Hin[(size_t)n * HID + k * 64 + t];
    float Mn[16];
    #pragma unroll
    for (int c = 0; c < 16; ++c) Mn[c] = M[(size_t)n * 16 + c];

    float acc[4];
    #pragma unroll
    for (int j = 0; j < 4; ++j)
        acc[j] = Mn[j*4+0]*Hn[0] + Mn[j*4+1]*Hn[1] + Mn[j*4+2]*Hn[2] + Mn[j*4+3]*Hn[3];

    sheaf_gather(inc, inc2, P, Hin, off[n], off[n + 1], t, acc);

    float xv[4];
    #pragma unroll
    for (int j = 0; j < 4; ++j) {
        size_t idx = (size_t)n * HID + j * 64 + t;
        float vv = h[idx] - fmaxf(acc[j], 0.f);
        h[idx] = vv;
        xv[j] = vv;
    }

    #pragma unroll
    for (int i = 0; i < 4; ++i)
        tl[w][i][t] = wd1[0 + i] * xv[0] + wd1[4 + i] * xv[1] +
                      wd1[8 + i] * xv[2] + wd1[12 + i] * xv[3];
    __syncthreads();
    float a0 = 0, a1 = 0, a2 = 0, a3 = 0;
    #pragma unroll
    for (int f = 0; f < 64; f += 4) {
        float4 wv = *(const float4*)&wt[t][f];
        float4 t0 = *(const float4*)&tl[w][0][f];
        float4 t1 = *(const float4*)&tl[w][1][f];
        float4 t2 = *(const float4*)&tl[w][2][f];
        float4 t3 = *(const float4*)&tl[w][3][f];
        a0 += t0.x * wv.x + t0.y * wv.y + t0.z * wv.z + t0.w * wv.w;
        a1 += t1.x * wv.x + t1.y * wv.y + t1.z * wv.z + t1.w * wv.w;
        a2 += t2.x * wv.x + t2.y * wv.y + t2.z * wv.z + t2.w * wv.w;
        a3 += t3.x * wv.x + t3.y * wv.y + t3.z * wv.z + t3.w * wv.w;
    }
    size_t base = (size_t)n * HID + t;
    Hout[base + 0 * 64] = a0;
    Hout[base + 1 * 64] = a1;
    Hout[base + 2 * 64] = a2;
    Hout[base + 3 * 64] = a3;
}

// ===========================================================================
// k_sheaf1 — layer 1: LH gather + xb update only. ZERO LDS.
// ===========================================================================
__global__ __launch_bounds__(256) void k_sheaf1(
    const int* __restrict__ inc, const int* __restrict__ inc2, const int* __restrict__ off,
    const float* __restrict__ P, const float* __restrict__ M,
    const float* __restrict__ Hin, float* __restrict__ h)
{
    const int tid = threadIdx.x;
    const int w = tid >> 6, t = tid & 63;
    const int n = blockIdx.x * 4 + w;

    float Hn[4];
    #pragma unroll
    for (int k = 0; k < 4; ++k) Hn[k] = Hin[(size_t)n * HID + k * 64 + t];
    float Mn[16];
    #pragma unroll
    for (int c = 0; c < 16; ++c) Mn[c] = M[(size_t)n * 16 + c];

    float acc[4];
    #pragma unroll
    for (int j = 0; j < 4; ++j)
        acc[j] = Mn[j*4+0]*Hn[0] + Mn[j*4+1]*Hn[1] + Mn[j*4+2]*Hn[2] + Mn[j*4+3]*Hn[3];

    sheaf_gather(inc, inc2, P, Hin, off[n], off[n + 1], t, acc);

    #pragma unroll
    for (int j = 0; j < 4; ++j) {
        size_t idx = (size_t)n * HID + j * 64 + t;
        h[idx] = h[idx] - fmaxf(acc[j], 0.f);
    }
}

// ===========================================================================
// k_out1: t1o = relu(xb @ Wo1.T + bo1).  grid (N/64, 4).
// ===========================================================================
__global__ __launch_bounds__(256, 4) void k_out1(
    const float* __restrict__ xb, const float* __restrict__ Wo1, const float* __restrict__ bo1,
    float* __restrict__ t1o)
{
    __shared__ float xr[64 * 129];
    const int tid  = threadIdx.x;
    const int w    = __builtin_amdgcn_readfirstlane(tid >> 6);
    const int lane = tid & 63;
    const int node0 = blockIdx.x * 64;
    const int cbase = blockIdx.y * 16 + w * 4;
    const int g = min(node0 + lane, NN - 1);
    const bool valid = (node0 + lane) < NN;

    float acc[4] = {0.f, 0.f, 0.f, 0.f};

    for (int j = 0; j < 2; ++j) {
        __syncthreads();
        for (int i = tid; i < 2048; i += 256) {
            int n = i >> 5, k4 = i & 31;
            int gr = min(node0 + n, NN - 1);
            float4 v = ((const float4*)xb)[(size_t)gr * 64 + j * 32 + k4];
            float* d = &xr[n * 129 + k4 * 4];
            d[0] = v.x; d[1] = v.y; d[2] = v.z; d[3] = v.w;
        }
        __syncthreads();
        for (int kt = 0; kt < 32; ++kt) {
            float x0 = xr[lane * 129 + kt * 4 + 0];
            float x1 = xr[lane * 129 + kt * 4 + 1];
            float x2 = xr[lane * 129 + kt * 4 + 2];
            float x3 = xr[lane * 129 + kt * 4 + 3];
            #pragma unroll
            for (int cc = 0; cc < 4; ++cc) {
                const float* wr = Wo1 + (size_t)(cbase + cc) * HID + j * 128 + kt * 4;
                acc[cc] += x0 * wr[0] + x1 * wr[1] + x2 * wr[2] + x3 * wr[3];
            }
        }
    }
    if (valid) {
        float4 v;
        v.x = fmaxf(acc[0] + bo1[cbase + 0], 0.f);
        v.y = fmaxf(acc[1] + bo1[cbase + 1], 0.f);
        v.z = fmaxf(acc[2] + bo1[cbase + 2], 0.f);
        v.w = fmaxf(acc[3] + bo1[cbase + 3], 0.f);
        *(float4*)(t1o + (size_t)g * MH + cbase) = v;
    }
}

// ===========================================================================
// k_out2: out = t1o @ Wo2.T + bo2.
// ===========================================================================
__global__ __launch_bounds__(256, 4) void k_out2(
    const float* __restrict__ t1o, const float* __restrict__ Wo2, const float* __restrict__ bo2,
    float* __restrict__ out)
{
    __shared__ float ts[64 * 65];
    const int tid  = threadIdx.x;
    const int lane = tid & 63;
    const int node0 = blockIdx.x * 64;
    const int g = min(node0 + lane, NN - 1);
    const bool valid = (node0 + lane) < NN;

    for (int i = tid; i < 1024; i += 256) {
        int n = i >> 4, k4 = i & 15;
        int gr = min(node0 + n, NN - 1);
        float4 v = ((const float4*)t1o)[(size_t)gr * 16 + k4];
        float* d = &ts[n * 65 + k4 * 4];
        d[0] = v.x; d[1] = v.y; d[2] = v.z; d[3] = v.w;
    }
    __syncthreads();

    float acc[16];
    #pragma unroll
    for (int i = 0; i < 16; ++i) acc[i] = 0.f;
    for (int kt = 0; kt < 8; ++kt) {
        float tv[8];
        #pragma unroll
        for (int i = 0; i < 8; ++i) tv[i] = ts[lane * 65 + kt * 8 + i];
        #pragma unroll
        for (int jj = 0; jj < 16; ++jj) {
            const float* wr = Wo2 + (size_t)jj * MH + kt * 8;
            acc[jj] += tv[0]*wr[0] + tv[1]*wr[1] + tv[2]*wr[2] + tv[3]*wr[3]
                     + tv[4]*wr[4] + tv[5]*wr[5] + tv[6]*wr[6] + tv[7]*wr[7];
        }
    }
    if (valid) {
        float* op = out + (size_t)g * OUT_D;
        #pragma unroll
        for (int c4 = 0; c4 < 4; ++c4) {
            float4 v;
            v.x = acc[c4*4+0] + bo2[c4*4+0];
            v.y = acc[c4*4+1] + bo2[c4*4+1];
            v.z = acc[c4*4+2] + bo2[c4*4+2];
            v.w = acc[c4*4+3] + bo2[c4*4+3];
            *(float4*)(op + c4 * 4) = v;
        }
    }
}

// ---------------------------------------------------------------------------
// Workspace layout (~89.2 MB). t1=H0, t1o=H1 aliases.
// ---------------------------------------------------------------------------
extern "C" void kernel_launch(void* const* d_in, const int* in_sizes, int n_in,
                              void* d_out, int out_size, void* d_ws, size_t ws_size,
                              hipStream_t stream)
{
    const float* x    = (const float*)d_in[0];
    const int*   ei   = (const int*)d_in[1];
    const float* Win1 = (const float*)d_in[2];
    const float* bin1 = (const float*)d_in[3];
    const float* Win2 = (const float*)d_in[4];
    const float* bin2 = (const float*)d_in[5];
    const float* Wm1  = (const float*)d_in[6];
    const float* bm1  = (const float*)d_in[7];
    const float* Wm2  = (const float*)d_in[8];
    const float* bm2  = (const float*)d_in[9];
    const float* Wd1  = (const float*)d_in[10];
    const float* Wd2  = (const float*)d_in[11];
    const float* Wo1  = (const float*)d_in[12];
    const float* bo1  = (const float*)d_in[13];
    const float* Wo2  = (const float*)d_in[14];
    const float* bo2  = (const float*)d_in[15];
    float* out = (float*)d_out;

    float* ws = (float*)d_ws;
    float* h  = ws;                            // N*256
    float* As = h  + (size_t)NN * HID;         // N*64
    float* Bs = As + (size_t)NN * MH;          // N*64
    float* H0 = Bs + (size_t)NN * MH;          // N*256
    float* H1 = H0 + (size_t)NN * HID;         // N*256
    float* P  = H1 + (size_t)NN * HID;         // E*16
    float* M  = P  + (size_t)EE * 16;          // N*16
    int* deg    = (int*)(M + (size_t)NN * 16); // N
    int* off    = deg + NN;                    // N+1
    int* cursor = off + NN + 1;                // N
    int* inc    = cursor + NN;                 // 2E
    int* inc2   = inc + 2 * EE;                // 2E
    float* t1  = H0;                           // alias
    float* t1o = H1;                           // alias

    const int NB = (NN + 63) / 64;             // 313

    // CSR build + M zero
    hipMemsetAsync(deg, 0, NN * sizeof(int), stream);
    hipMemsetAsync(M, 0, (size_t)NN * 16 * sizeof(float), stream);
    k_deg<<<(EE + 255) / 256, 256, 0, stream>>>(ei, deg);
    k_scan<<<1, 256, 0, stream>>>(deg, off, cursor);
    k_scatter<<<(EE + 255) / 256, 256, 0, stream>>>(ei, cursor, inc, inc2);

    // node MLP + per-edge P/Q/R
    k_mlp1<<<dim3(NB, 4), 256, 0, stream>>>(x, Win1, bin1, t1);
    k_mlp2<<<dim3(NB, 4), 256, 0, stream>>>(t1, Win2, bin2, h);
    k_mlp3<<<dim3(NB, 4), 256, 0, stream>>>(h, Wm1, As, Bs);
    k_edge_msg<<<EE / 64, 256, 0, stream>>>(ei, As, Bs, bm1, Wm2, bm2, P, M);

    // diffusion
    k_node_H<<<NN / 16, 256, 0, stream>>>(h, Wd1, Wd2, H0);
    k_sheaf0<<<NN / 4, 256, 0, stream>>>(inc, inc2, off, P, M, H0, h, H1,
                                         Wd1 + 16, Wd2 + 4096);
    k_sheaf1<<<NN / 4, 256, 0, stream>>>(inc, inc2, off, P, M, H1, h);

    // output MLP
    k_out1<<<dim3(NB, 4), 256, 0, stream>>>(h, Wo1, bo1, t1o);
    k_out2<<<NB, 256, 0, stream>>>(t1o, Wo2, bo2, out);
}